// Round 10
// baseline (206.866 us; speedup 1.0000x reference)
//
#include <hip/hip_runtime.h>
#include <hip/hip_bf16.h>

#define NUM_HEADS   32
#define NUM_KV_HEADS 8
#define HEAD_DIM    128
#define GQA          4
#define Q_LEN      256
#define MAX_PAGES  128
#define PAGE_SIZE   16
#define SCALE 0.08838834764831845f
#define LOG2E 1.44269504088896340736f
#define RESCALE_THR 8.0f
#define NEGINF (-__builtin_inff())

// 64-token chunks
#define NCH_MAX   36
#define CHUNK_B   16384
#define KSTREAM   ((size_t)NCH_MAX * CHUNK_B)
#define NITEMS    256                     // b(8) x kvh(8) x grp(4); grp = 2 s32 blocks
#define PBYTES    67584                   // 65536 B bf16 O (frag order) + 2048 B ml

typedef __bf16 bf16x8 __attribute__((ext_vector_type(8)));
typedef float  f32x4  __attribute__((ext_vector_type(4)));

union B8 { uint4 u; bf16x8 v; };

__device__ __forceinline__ unsigned f2bf(float x){
    unsigned u = __builtin_bit_cast(unsigned, x);
    return (u + 0x7fffu + ((u >> 16) & 1u)) >> 16;
}
__device__ __forceinline__ unsigned pack2(float lo, float hi){
    return f2bf(lo) | (f2bf(hi) << 16);
}
__device__ __forceinline__ float bflo(unsigned h){
    return __builtin_bit_cast(float, h << 16);
}
__device__ __forceinline__ float bfhi(unsigned h){
    return __builtin_bit_cast(float, h & 0xffff0000u);
}

typedef __attribute__((address_space(3))) unsigned char lds_as3_t;
typedef const __attribute__((address_space(1))) void gas_v;
typedef __attribute__((address_space(3))) void las_v;

#define GLD16(g, l) __builtin_amdgcn_global_load_lds((gas_v*)(g), (las_v*)(l), 16, 0, 0)

#define TRR(dst, base, OFF) asm volatile("ds_read_b64_tr_b16 %0, %1 offset:" OFF \
                                         : "=v"(dst) : "v"(base))

// ============================ pre-pass: gather + bf16 + pre-swizzle (64-t chunks) ============================
__global__ __launch_bounds__(256) void prep_kernel(
    const float* __restrict__ knew,
    const float* __restrict__ vnew,
    const float* __restrict__ kcache,
    const float* __restrict__ vcache,
    const int*   __restrict__ ptab,
    const int*   __restrict__ ctxlens,
    unsigned char* __restrict__ kimg,
    unsigned char* __restrict__ vimg)
{
    const int ch  = blockIdx.x;
    const int kvh = blockIdx.y;
    const int b   = blockIdx.z;
    const int ctxlen = ctxlens[b];
    const int lim = ctxlen + Q_LEN;
    const int base = ch * 64;
    if (base >= lim) return;

    const int tid  = threadIdx.x;
    const int srow = tid >> 2;
    const int seg  = tid & 3;
    const int t    = base + srow;

    unsigned char* kdst = kimg + (size_t)(b * 8 + kvh) * KSTREAM + (size_t)ch * CHUNK_B;
    unsigned char* vdst = vimg + (size_t)(b * 8 + kvh) * KSTREAM + (size_t)ch * CHUNK_B;
    const int swz    = (srow & 7) << 4;
    const int vbyte0 = (srow >> 2) * 128 + (srow & 3) * 32;

    if (t < lim){
        size_t roff;
        const float *ksrc, *vsrc;
        if (t < ctxlen){
            const int page = ptab[b * MAX_PAGES + (t >> 4)];
            roff = ((size_t)(page * PAGE_SIZE + (t & 15)) * NUM_KV_HEADS + kvh) * HEAD_DIM;
            ksrc = kcache + roff; vsrc = vcache + roff;
        } else {
            roff = ((size_t)(b * Q_LEN + (t - ctxlen)) * NUM_KV_HEADS + kvh) * HEAD_DIM;
            ksrc = knew + roff; vsrc = vnew + roff;
        }
        const float* kr = ksrc + seg * 32;
        const float* vr = vsrc + seg * 32;
        #pragma unroll
        for (int i = 0; i < 4; ++i){
            float4 a  = *(const float4*)(kr + i * 8);
            float4 c4 = *(const float4*)(kr + i * 8 + 4);
            uint4 wv;
            wv.x = pack2(a.x, a.y);  wv.y = pack2(a.z, a.w);
            wv.z = pack2(c4.x, c4.y); wv.w = pack2(c4.z, c4.w);
            *(uint4*)(kdst + srow * 256 + ((seg * 64 + i * 16) ^ swz)) = wv;
        }
        #pragma unroll
        for (int db = 0; db < 2; ++db){
            const float4 a0 = *(const float4*)(vr + db * 16 + 0);
            const float4 a1 = *(const float4*)(vr + db * 16 + 4);
            const float4 a2 = *(const float4*)(vr + db * 16 + 8);
            const float4 a3 = *(const float4*)(vr + db * 16 + 12);
            uint4 w0, w1;
            w0.x = pack2(a0.x, a0.y); w0.y = pack2(a0.z, a0.w);
            w0.z = pack2(a1.x, a1.y); w0.w = pack2(a1.z, a1.w);
            w1.x = pack2(a2.x, a2.y); w1.y = pack2(a2.z, a2.w);
            w1.z = pack2(a3.x, a3.y); w1.w = pack2(a3.z, a3.w);
            const int dbk = seg * 2 + db;
            *(uint4*)(vdst + dbk * 2048 + vbyte0)      = w0;
            *(uint4*)(vdst + dbk * 2048 + vbyte0 + 16) = w1;
        }
    } else {
        const uint4 z = {0u, 0u, 0u, 0u};
        #pragma unroll
        for (int i = 0; i < 4; ++i)
            *(uint4*)(kdst + srow * 256 + ((seg * 64 + i * 16) ^ swz)) = z;
        #pragma unroll
        for (int db = 0; db < 2; ++db){
            const int dbk = seg * 2 + db;
            *(uint4*)(vdst + dbk * 2048 + vbyte0)      = z;
            *(uint4*)(vdst + dbk * 2048 + vbyte0 + 16) = z;
        }
    }
}

// ============================ attention kernel: 8 waves = 4 heads x 2 s32-tiles ============================
// LDS 64KB: K dbuf [2][16KB] at 0, V dbuf [2][16KB] at 32768. 2 blocks/CU = 16 waves/CU.
template<int NSPLIT>
__global__ __launch_bounds__(512, 4) void attn_kernel(
    const float* __restrict__ q,
    const int*   __restrict__ ctxlens,
    float*       __restrict__ out,
    const unsigned char* __restrict__ kimg,
    const unsigned char* __restrict__ vimg,
    unsigned char* __restrict__ part)
{
    __shared__ __align__(16) unsigned char lds[65536];

    const int tid  = threadIdx.x;
    const int w8   = tid >> 6;      // 0..7
    const int lane = tid & 63;
    const int hh   = lane >> 4;
    const int cq   = lane & 15;
    const int head = w8 & 3;        // GQA head within group
    const int p    = w8 >> 2;       // which s32 of the pair

    const unsigned ldsb3 = (unsigned)(unsigned long long)(lds_as3_t*)(&lds[0]);

    const int fid   = blockIdx.x;
    const int item0 = fid / NSPLIT;
    const int seg   = fid % NSPLIT;

    const int b   = item0 & 7;
    const int kvh = (item0 >> 3) & 7;
    const int g   = 3 - (item0 >> 6);          // long groups dispatched first

    const int ctxlen = ctxlens[b];
    const int vlim = ctxlen + (2 * g + p + 1) * 32;    // per-wave visibility
    const int vmax = ctxlen + (2 * g + 2) * 32;
    const int nch  = (vmax + 63) >> 6;
    const int lo   = (seg * nch) / NSPLIT;
    const int hi   = ((seg + 1) * nch) / NSPLIT;
    if (lo >= hi) return;                       // uniform per block
    const int hq  = kvh * GQA + head;
    const int s0w = (2 * g + p) * 32;

    const unsigned char* kstream = kimg + (size_t)(b * 8 + kvh) * KSTREAM;
    const unsigned char* vstream = vimg + (size_t)(b * 8 + kvh) * KSTREAM;

    // 4 GLD16 per thread per chunk; dest = wave-uniform base (HW adds lane*16)
    #define STAGE(CH, PB) do { \
        const unsigned char* kg_ = kstream + (size_t)(CH) * CHUNK_B + (w8 * 1024 + lane * 16); \
        const unsigned char* vg_ = vstream + (size_t)(CH) * CHUNK_B + (w8 * 1024 + lane * 16); \
        _Pragma("unroll") \
        for (int i_ = 0; i_ < 2; ++i_){ \
            GLD16(kg_ + i_ * 8192, lds + (PB) * 16384 + w8 * 1024 + i_ * 8192); \
            GLD16(vg_ + i_ * 8192, lds + 32768 + (PB) * 16384 + w8 * 1024 + i_ * 8192); \
        } \
    } while (0)

    STAGE(lo, lo & 1);

    // Q fragments (B-operand), two 16-row tiles, pre-scaled into log2 domain
    B8 qf[2][4];
    #pragma unroll
    for (int u = 0; u < 2; ++u){
        const float* qrow = q + (size_t)(b * Q_LEN + s0w + u * 16 + cq) * (NUM_HEADS * HEAD_DIM)
                              + hq * HEAD_DIM;
        #pragma unroll
        for (int c = 0; c < 4; ++c){
            const float4 f0 = *(const float4*)(qrow + c * 32 + 8 * hh);
            const float4 f1 = *(const float4*)(qrow + c * 32 + 8 * hh + 4);
            const float sc = SCALE * LOG2E;
            qf[u][c].u.x = pack2(f0.x * sc, f0.y * sc);
            qf[u][c].u.y = pack2(f0.z * sc, f0.w * sc);
            qf[u][c].u.z = pack2(f1.x * sc, f1.y * sc);
            qf[u][c].u.w = pack2(f1.z * sc, f1.w * sc);
        }
    }

    f32x4 acc[2][8] = {};
    float mrun[2] = {-1e30f, -1e30f};
    float lp[2]   = {0.f, 0.f};

    __syncthreads();   // buffer (lo&1) ready (implicit vmcnt(0) drain)

    for (int ch = lo; ch < hi; ++ch){
        const int pb = ch & 1;
        if (ch + 1 < hi) STAGE(ch + 1, pb ^ 1);

        const int base = ch * 64;
        const unsigned kb = (unsigned)(pb * 16384);

        // ---------------- QK^T (swapped): st[u][tf] = S^T[t][q] ----------------
        __builtin_amdgcn_s_setprio(1);
        f32x4 st[2][4] = {};
        #pragma unroll
        for (int c = 0; c < 4; ++c){
            #pragma unroll
            for (int tf = 0; tf < 4; ++tf){
                const int trow = tf * 16 + cq;
                const unsigned byte = kb + trow * 256 + ((c * 64 + hh * 16) ^ ((trow & 7) << 4));
                B8 kf; kf.u = *(const uint4*)(lds + byte);
                st[0][tf] = __builtin_amdgcn_mfma_f32_16x16x32_bf16(kf.v, qf[0][c].v, st[0][tf], 0, 0, 0);
                st[1][tf] = __builtin_amdgcn_mfma_f32_16x16x32_bf16(kf.v, qf[1][c].v, st[1][tf], 0, 0, 0);
            }
        }
        __builtin_amdgcn_s_setprio(0);

        // ---------------- softmax (shuffle-free defer-max + deferred-l, base-2) ----------------
        B8 af[2][2];
        const bool interior = (base + 64 <= vlim);
        #pragma unroll
        for (int u = 0; u < 2; ++u){
            float pv[4][4];
            float pml = NEGINF;             // per-lane partial max (16 t's)
            if (interior){
                #pragma unroll
                for (int tf = 0; tf < 4; ++tf){
                    #pragma unroll
                    for (int r = 0; r < 4; ++r){
                        const float s = st[u][tf][r];
                        pv[tf][r] = s;
                        pml = fmaxf(pml, s);
                    }
                }
            } else {
                #pragma unroll
                for (int tf = 0; tf < 4; ++tf){
                    #pragma unroll
                    for (int r = 0; r < 4; ++r){
                        const int t = base + tf * 16 + hh * 4 + r;
                        const float s = (t < vlim) ? st[u][tf][r] : NEGINF;
                        pv[tf][r] = s;
                        pml = fmaxf(pml, s);
                    }
                }
            }
            // wave-uniform rescale test without cross-lane reduce:
            // all partial maxes <= thr  <=>  wave max <= thr
            if (!__all(pml <= mrun[u] + RESCALE_THR)){
                float pm = fmaxf(pml, __shfl_xor(pml, 16));
                pm = fmaxf(pm, __shfl_xor(pm, 32));
                const float mnew  = fmaxf(mrun[u], pm);
                const float alpha = __builtin_amdgcn_exp2f(mrun[u] - mnew);
                mrun[u] = mnew;
                lp[u] *= alpha;
                float a4[4];
                #pragma unroll
                for (int r = 0; r < 4; ++r) a4[r] = __shfl(alpha, hh * 20 + r);
                #pragma unroll
                for (int dc = 0; dc < 8; ++dc){
                    #pragma unroll
                    for (int r = 0; r < 4; ++r) acc[u][dc][r] *= a4[r];
                }
            }
            const float m = mrun[u];
            float rsum = 0.f;
            #pragma unroll
            for (int tf = 0; tf < 4; ++tf){
                #pragma unroll
                for (int r = 0; r < 4; ++r){
                    const float e = __builtin_amdgcn_exp2f(pv[tf][r] - m);
                    pv[tf][r] = e;
                    rsum += e;
                }
            }
            lp[u] += rsum;

            // k-axis mapping: t(kk, 8hh+j) = 32kk + 16*(j>>2) + 4hh + (j&3)
            unsigned pk01[4], pk23[4];
            #pragma unroll
            for (int tf = 0; tf < 4; ++tf){
                pk01[tf] = pack2(pv[tf][0], pv[tf][1]);
                pk23[tf] = pack2(pv[tf][2], pv[tf][3]);
            }
            af[u][0].u.x = pk01[0]; af[u][0].u.y = pk23[0]; af[u][0].u.z = pk01[1]; af[u][0].u.w = pk23[1];
            af[u][1].u.x = pk01[2]; af[u][1].u.y = pk23[2]; af[u][1].u.z = pk01[3]; af[u][1].u.w = pk23[3];
        }

        // ---------------- PV via hardware transpose reads; vf shared by tiles ----------------
        {
            const unsigned trb = ldsb3 + 32768u + (unsigned)(pb * 16384) + (unsigned)(hh * 128 + cq * 8);
            unsigned long long r0,r1,r2,r3,r4,r5,r6,r7;
            B8 vf;
            __builtin_amdgcn_s_setprio(1);
            // ---- kk=0, dc=0..3 ----
            TRR(r0, trb, "0");     TRR(r1, trb, "512");
            TRR(r2, trb, "2048");  TRR(r3, trb, "2560");
            TRR(r4, trb, "4096");  TRR(r5, trb, "4608");
            TRR(r6, trb, "6144");  TRR(r7, trb, "6656");
            asm volatile("s_waitcnt lgkmcnt(0)" ::: "memory");
            __builtin_amdgcn_sched_barrier(0);
            vf.u.x=(unsigned)r0; vf.u.y=(unsigned)(r0>>32); vf.u.z=(unsigned)r1; vf.u.w=(unsigned)(r1>>32);
            acc[0][0] = __builtin_amdgcn_mfma_f32_16x16x32_bf16(af[0][0].v, vf.v, acc[0][0], 0, 0, 0);
            acc[1][0] = __builtin_amdgcn_mfma_f32_16x16x32_bf16(af[1][0].v, vf.v, acc[1][0], 0, 0, 0);
            vf.u.x=(unsigned)r2; vf.u.y=(unsigned)(r2>>32); vf.u.z=(unsigned)r3; vf.u.w=(unsigned)(r3>>32);
            acc[0][1] = __builtin_amdgcn_mfma_f32_16x16x32_bf16(af[0][0].v, vf.v, acc[0][1], 0, 0, 0);
            acc[1][1] = __builtin_amdgcn_mfma_f32_16x16x32_bf16(af[1][0].v, vf.v, acc[1][1], 0, 0, 0);
            vf.u.x=(unsigned)r4; vf.u.y=(unsigned)(r4>>32); vf.u.z=(unsigned)r5; vf.u.w=(unsigned)(r5>>32);
            acc[0][2] = __builtin_amdgcn_mfma_f32_16x16x32_bf16(af[0][0].v, vf.v, acc[0][2], 0, 0, 0);
            acc[1][2] = __builtin_amdgcn_mfma_f32_16x16x32_bf16(af[1][0].v, vf.v, acc[1][2], 0, 0, 0);
            vf.u.x=(unsigned)r6; vf.u.y=(unsigned)(r6>>32); vf.u.z=(unsigned)r7; vf.u.w=(unsigned)(r7>>32);
            acc[0][3] = __builtin_amdgcn_mfma_f32_16x16x32_bf16(af[0][0].v, vf.v, acc[0][3], 0, 0, 0);
            acc[1][3] = __builtin_amdgcn_mfma_f32_16x16x32_bf16(af[1][0].v, vf.v, acc[1][3], 0, 0, 0);
            // ---- kk=0, dc=4..7 ----
            TRR(r0, trb, "8192");  TRR(r1, trb, "8704");
            TRR(r2, trb, "10240"); TRR(r3, trb, "10752");
            TRR(r4, trb, "12288"); TRR(r5, trb, "12800");
            TRR(r6, trb, "14336"); TRR(r7, trb, "14848");
            asm volatile("s_waitcnt lgkmcnt(0)" ::: "memory");
            __builtin_amdgcn_sched_barrier(0);
            vf.u.x=(unsigned)r0; vf.u.y=(unsigned)(r0>>32); vf.u.z=(unsigned)r1; vf.u.w=(unsigned)(r1>>32);
            acc[0][4] = __builtin_amdgcn_mfma_f32_16x16x32_bf16(af[0][0].v, vf.v, acc[0][4], 0, 0, 0);
            acc[1][4] = __builtin_amdgcn_mfma_f32_16x16x32_bf16(af[1][0].v, vf.v, acc[1][4], 0, 0, 0);
            vf.u.x=(unsigned)r2; vf.u.y=(unsigned)(r2>>32); vf.u.z=(unsigned)r3; vf.u.w=(unsigned)(r3>>32);
            acc[0][5] = __builtin_amdgcn_mfma_f32_16x16x32_bf16(af[0][0].v, vf.v, acc[0][5], 0, 0, 0);
            acc[1][5] = __builtin_amdgcn_mfma_f32_16x16x32_bf16(af[1][0].v, vf.v, acc[1][5], 0, 0, 0);
            vf.u.x=(unsigned)r4; vf.u.y=(unsigned)(r4>>32); vf.u.z=(unsigned)r5; vf.u.w=(unsigned)(r5>>32);
            acc[0][6] = __builtin_amdgcn_mfma_f32_16x16x32_bf16(af[0][0].v, vf.v, acc[0][6], 0, 0, 0);
            acc[1][6] = __builtin_amdgcn_mfma_f32_16x16x32_bf16(af[1][0].v, vf.v, acc[1][6], 0, 0, 0);
            vf.u.x=(unsigned)r6; vf.u.y=(unsigned)(r6>>32); vf.u.z=(unsigned)r7; vf.u.w=(unsigned)(r7>>32);
            acc[0][7] = __builtin_amdgcn_mfma_f32_16x16x32_bf16(af[0][0].v, vf.v, acc[0][7], 0, 0, 0);
            acc[1][7] = __builtin_amdgcn_mfma_f32_16x16x32_bf16(af[1][0].v, vf.v, acc[1][7], 0, 0, 0);
            // ---- kk=1, dc=0..3 ----
            TRR(r0, trb, "1024");  TRR(r1, trb, "1536");
            TRR(r2, trb, "3072");  TRR(r3, trb, "3584");
            TRR(r4, trb, "5120");  TRR(r5, trb, "5632");
            TRR(r6, trb, "7168");  TRR(r7, trb, "7680");
            asm volatile("s_waitcnt lgkmcnt(0)" ::: "memory");
            __builtin_amdgcn_sched_barrier(0);
            vf.u.x=(unsigned)r0; vf.u.y=(unsigned)(r0>>32); vf.u.z=(unsigned)r1; vf.u.w=(unsigned)(r1>>32);
            acc[0][0] = __builtin_amdgcn_mfma_f32_16x16x32_bf16(af[0][1].v, vf.v, acc[0][0], 0, 0, 0);
            acc[1][0] = __builtin_amdgcn_mfma_f32_16x16x32_bf16(af[1][1].v, vf.v, acc[1][0], 0, 0, 0);
            vf.u.x=(unsigned)r2; vf.u.y=(unsigned)(r2>>32); vf.u.z=(unsigned)r3; vf.u.w=(unsigned)(r3>>32);
            acc[0][1] = __builtin_amdgcn_mfma_f32_16x16x32_bf16(af[0][1].v, vf.v, acc[0][1], 0, 0, 0);
            acc[1][1] = __builtin_amdgcn_mfma_f32_16x16x32_bf16(af[1][1].v, vf.v, acc[1][1], 0, 0, 0);
            vf.u.x=(unsigned)r4; vf.u.y=(unsigned)(r4>>32); vf.u.z=(unsigned)r5; vf.u.w=(unsigned)(r5>>32);
            acc[0][2] = __builtin_amdgcn_mfma_f32_16x16x32_bf16(af[0][1].v, vf.v, acc[0][2], 0, 0, 0);
            acc[1][2] = __builtin_amdgcn_mfma_f32_16x16x32_bf16(af[1][1].v, vf.v, acc[1][2], 0, 0, 0);
            vf.u.x=(unsigned)r6; vf.u.y=(unsigned)(r6>>32); vf.u.z=(unsigned)r7; vf.u.w=(unsigned)(r7>>32);
            acc[0][3] = __builtin_amdgcn_mfma_f32_16x16x32_bf16(af[0][1].v, vf.v, acc[0][3], 0, 0, 0);
            acc[1][3] = __builtin_amdgcn_mfma_f32_16x16x32_bf16(af[1][1].v, vf.v, acc[1][3], 0, 0, 0);
            // ---- kk=1, dc=4..7 ----
            TRR(r0, trb, "9216");  TRR(r1, trb, "9728");
            TRR(r2, trb, "11264"); TRR(r3, trb, "11776");
            TRR(r4, trb, "13312"); TRR(r5, trb, "13824");
            TRR(r6, trb, "15360"); TRR(r7, trb, "15872");
            asm volatile("s_waitcnt lgkmcnt(0)" ::: "memory");
            __builtin_amdgcn_sched_barrier(0);
            vf.u.x=(unsigned)r0; vf.u.y=(unsigned)(r0>>32); vf.u.z=(unsigned)r1; vf.u.w=(unsigned)(r1>>32);
            acc[0][4] = __builtin_amdgcn_mfma_f32_16x16x32_bf16(af[0][1].v, vf.v, acc[0][4], 0, 0, 0);
            acc[1][4] = __builtin_amdgcn_mfma_f32_16x16x32_bf16(af[1][1].v, vf.v, acc[1][4], 0, 0, 0);
            vf.u.x=(unsigned)r2; vf.u.y=(unsigned)(r2>>32); vf.u.z=(unsigned)r3; vf.u.w=(unsigned)(r3>>32);
            acc[0][5] = __builtin_amdgcn_mfma_f32_16x16x32_bf16(af[0][1].v, vf.v, acc[0][5], 0, 0, 0);
            acc[1][5] = __builtin_amdgcn_mfma_f32_16x16x32_bf16(af[1][1].v, vf.v, acc[1][5], 0, 0, 0);
            vf.u.x=(unsigned)r4; vf.u.y=(unsigned)(r4>>32); vf.u.z=(unsigned)r5; vf.u.w=(unsigned)(r5>>32);
            acc[0][6] = __builtin_amdgcn_mfma_f32_16x16x32_bf16(af[0][1].v, vf.v, acc[0][6], 0, 0, 0);
            acc[1][6] = __builtin_amdgcn_mfma_f32_16x16x32_bf16(af[1][1].v, vf.v, acc[1][6], 0, 0, 0);
            vf.u.x=(unsigned)r6; vf.u.y=(unsigned)(r6>>32); vf.u.z=(unsigned)r7; vf.u.w=(unsigned)(r7>>32);
            acc[0][7] = __builtin_amdgcn_mfma_f32_16x16x32_bf16(af[0][1].v, vf.v, acc[0][7], 0, 0, 0);
            acc[1][7] = __builtin_amdgcn_mfma_f32_16x16x32_bf16(af[1][1].v, vf.v, acc[1][7], 0, 0, 0);
            __builtin_amdgcn_s_setprio(0);
        }
        __syncthreads();
    }

    // ---------------- epilogue ----------------
    if (NSPLIT == 1){
        #pragma unroll
        for (int u = 0; u < 2; ++u){
            float l = lp[u];
            l += __shfl_xor(l, 16);
            l += __shfl_xor(l, 32);
            const float li = 1.0f / l;
            float li4[4];
            #pragma unroll
            for (int r = 0; r < 4; ++r) li4[r] = __shfl(li, hh * 20 + r);
            #pragma unroll
            for (int dc = 0; dc < 8; ++dc){
                #pragma unroll
                for (int r = 0; r < 4; ++r){
                    const int so = s0w + u * 16 + hh * 4 + r;
                    out[(size_t)(b * Q_LEN + so) * (NUM_HEADS * HEAD_DIM) + hq * HEAD_DIM + dc * 16 + cq]
                        = acc[u][dc][r] * li4[r];
                }
            }
        }
    } else {
        // bf16 fragment-order partial: fully coalesced
        unsigned char* pp = part + (size_t)fid * PBYTES;
        #pragma unroll
        for (int u = 0; u < 2; ++u){
            float l = lp[u];
            l += __shfl_xor(l, 16);
            l += __shfl_xor(l, 32);
            if (hh == 0){
                float2 ml; ml.x = mrun[u]; ml.y = l;
                *(float2*)(pp + 65536 + (size_t)(head * 64 + p * 32 + u * 16 + cq) * 8) = ml;
            }
            #pragma unroll
            for (int dc = 0; dc < 8; ++dc){
                uint2 pk;
                pk.x = pack2(acc[u][dc][0], acc[u][dc][1]);
                pk.y = pack2(acc[u][dc][2], acc[u][dc][3]);
                *(uint2*)(pp + (size_t)((((head * 4 + p * 2 + u) * 8 + dc) * 64 + lane)) * 8) = pk;
            }
        }
    }
    #undef STAGE
}

// ============================ merge kernel (coalesced, bf16 partials) ============================
template<int NSPLIT>
__global__ __launch_bounds__(256) void merge_kernel(
    const int* __restrict__ ctxlens,
    const unsigned char* __restrict__ part,
    float* __restrict__ out)
{
    __shared__ float s_w[NSPLIT][256];

    const int item0 = blockIdx.x;
    const int b   = item0 & 7;
    const int kvh = (item0 >> 3) & 7;
    const int g   = 3 - (item0 >> 6);
    const int vmax = ctxlens[b] + (2 * g + 2) * 32;
    const int nch  = (vmax + 63) >> 6;

    const int tid = threadIdx.x;

    bool act[NSPLIT];
    #pragma unroll
    for (int s = 0; s < NSPLIT; ++s){
        const int lo = (s * nch) / NSPLIT;
        const int hi = ((s + 1) * nch) / NSPLIT;
        act[s] = hi > lo;
    }

    {
        float m[NSPLIT], l[NSPLIT];
        float M = NEGINF;
        #pragma unroll
        for (int s = 0; s < NSPLIT; ++s){
            if (act[s]){
                const float2 ml = *(const float2*)(part + (size_t)(item0 * NSPLIT + s) * PBYTES
                                                   + 65536 + (size_t)tid * 8);
                m[s] = ml.x; l[s] = ml.y;
                M = fmaxf(M, m[s]);
            }
        }
        float L = 0.f;
        float wg[NSPLIT];
        #pragma unroll
        for (int s = 0; s < NSPLIT; ++s){
            if (act[s]){
                wg[s] = __builtin_amdgcn_exp2f(m[s] - M);
                L += l[s] * wg[s];
            } else wg[s] = 0.f;
        }
        const float inv = 1.0f / L;
        #pragma unroll
        for (int s = 0; s < NSPLIT; ++s) s_w[s][tid] = wg[s] * inv;
    }
    __syncthreads();

    // O pass: 8192 uint2-slots = 4096 uint4; 16 per thread.
    for (int k = 0; k < 16; ++k){
        const int q4 = tid + k * 256;
        const int gidx = q4 >> 5;          // (head*4 + t2)*... in [0,128)
        const int head = gidx >> 5;
        const int t2   = (gidx >> 3) & 3;  // p*2 + u
        const int dc   = gidx & 7;
        const int ln   = (q4 * 2) & 63;
        const int hh   = ln >> 4;
        const int cq   = ln & 15;          // even
        const int wb   = head * 64 + t2 * 16 + hh * 4;

        float o0[4] = {0.f, 0.f, 0.f, 0.f};
        float o1[4] = {0.f, 0.f, 0.f, 0.f};
        #pragma unroll
        for (int s = 0; s < NSPLIT; ++s){
            if (!act[s]) continue;
            const uint4 v = *(const uint4*)(part + (size_t)(item0 * NSPLIT + s) * PBYTES
                                            + (size_t)q4 * 16);
            const float w0 = s_w[s][wb + 0];
            const float w1 = s_w[s][wb + 1];
            const float w2 = s_w[s][wb + 2];
            const float w3 = s_w[s][wb + 3];
            o0[0] += w0 * bflo(v.x); o0[1] += w1 * bfhi(v.x);
            o0[2] += w2 * bflo(v.y); o0[3] += w3 * bfhi(v.y);
            o1[0] += w0 * bflo(v.z); o1[1] += w1 * bfhi(v.z);
            o1[2] += w2 * bflo(v.w); o1[3] += w3 * bfhi(v.w);
        }
        float* obase = out + (size_t)(b * Q_LEN + g * 64 + t2 * 16 + hh * 4) * (NUM_HEADS * HEAD_DIM)
                     + (kvh * GQA + head) * HEAD_DIM + dc * 16 + cq;
        #pragma unroll
        for (int r = 0; r < 4; ++r){
            float2 ov; ov.x = o0[r]; ov.y = o1[r];
            *(float2*)(obase + (size_t)r * (NUM_HEADS * HEAD_DIM)) = ov;
        }
    }
}

extern "C" void kernel_launch(void* const* d_in, const int* in_sizes, int n_in,
                              void* d_out, int out_size, void* d_ws, size_t ws_size,
                              hipStream_t stream) {
    const float* q  = (const float*)d_in[0];
    const float* k  = (const float*)d_in[1];
    const float* v  = (const float*)d_in[2];
    const float* kc = (const float*)d_in[3];
    const float* vc = (const float*)d_in[4];
    const int*   pt = (const int*)d_in[5];
    const int*   cl = (const int*)d_in[6];
    float* o = (float*)d_out;

    const size_t img_bytes = (size_t)64 * KSTREAM;            // 37,748,736 per image
    const size_t off_part  = 256 + 2 * img_bytes;             // 75,497,728
    const size_t need2 = off_part + (size_t)NITEMS * 2 * PBYTES;   // ~110 MB
    const size_t need1 = off_part;

    unsigned char* kimg = (unsigned char*)d_ws + 256;
    unsigned char* vimg = kimg + img_bytes;
    unsigned char* part = (unsigned char*)d_ws + off_part;

    prep_kernel<<<dim3(NCH_MAX, 8, 8), 256, 0, stream>>>(k, v, kc, vc, pt, cl, kimg, vimg);

    if (ws_size >= need2) {
        attn_kernel<2><<<NITEMS * 2, 512, 0, stream>>>(q, cl, o, kimg, vimg, part);
        merge_kernel<2><<<NITEMS, 256, 0, stream>>>(cl, part, o);
    } else if (ws_size >= need1) {
        attn_kernel<1><<<NITEMS, 512, 0, stream>>>(q, cl, o, kimg, vimg, part);
    }
}

// Round 11
// 138.761 us; speedup vs baseline: 1.4908x; 1.4908x over previous
//
#include <hip/hip_runtime.h>
#include <hip/hip_bf16.h>

#define NUM_HEADS   32
#define NUM_KV_HEADS 8
#define HEAD_DIM    128
#define GQA          4
#define Q_LEN      256
#define MAX_PAGES  128
#define PAGE_SIZE   16
#define SCALE 0.08838834764831845f
#define LOG2E 1.44269504088896340736f
#define RESCALE_THR 8.0f

// 64-token chunks (best measured per-chunk economics)
#define NCH_MAX   36
#define CHUNK_B   16384
#define KSTREAM   ((size_t)NCH_MAX * CHUNK_B)
#define NITEMS    512
#define PBYTES    33792                   // 32768 B bf16 O (frag order) + 1024 B ml

typedef __bf16 bf16x8 __attribute__((ext_vector_type(8)));
typedef float  f32x4  __attribute__((ext_vector_type(4)));

union B8 { uint4 u; bf16x8 v; };

__device__ __forceinline__ unsigned f2bf(float x){
    unsigned u = __builtin_bit_cast(unsigned, x);
    return (u + 0x7fffu + ((u >> 16) & 1u)) >> 16;
}
__device__ __forceinline__ unsigned pack2(float lo, float hi){
    return f2bf(lo) | (f2bf(hi) << 16);
}
__device__ __forceinline__ float bflo(unsigned h){
    return __builtin_bit_cast(float, h << 16);
}
__device__ __forceinline__ float bfhi(unsigned h){
    return __builtin_bit_cast(float, h & 0xffff0000u);
}

typedef __attribute__((address_space(3))) unsigned char lds_as3_t;
typedef const __attribute__((address_space(1))) void gas_v;
typedef __attribute__((address_space(3))) void las_v;

#define GLD16(g, l) __builtin_amdgcn_global_load_lds((gas_v*)(g), (las_v*)(l), 16, 0, 0)

#define TRR(dst, base, OFF) asm volatile("ds_read_b64_tr_b16 %0, %1 offset:" OFF \
                                         : "=v"(dst) : "v"(base))

// ============================ pre-pass: gather + bf16 + pre-swizzle (64-t chunks) ============================
__global__ __launch_bounds__(256) void prep_kernel(
    const float* __restrict__ knew,
    const float* __restrict__ vnew,
    const float* __restrict__ kcache,
    const float* __restrict__ vcache,
    const int*   __restrict__ ptab,
    const int*   __restrict__ ctxlens,
    unsigned char* __restrict__ kimg,
    unsigned char* __restrict__ vimg)
{
    const int ch  = blockIdx.x;
    const int kvh = blockIdx.y;
    const int b   = blockIdx.z;
    const int ctxlen = ctxlens[b];
    const int lim = ctxlen + Q_LEN;
    const int base = ch * 64;
    if (base >= lim) return;

    const int tid  = threadIdx.x;
    const int srow = tid >> 2;
    const int seg  = tid & 3;
    const int t    = base + srow;

    unsigned char* kdst = kimg + (size_t)(b * 8 + kvh) * KSTREAM + (size_t)ch * CHUNK_B;
    unsigned char* vdst = vimg + (size_t)(b * 8 + kvh) * KSTREAM + (size_t)ch * CHUNK_B;
    const int swz    = (srow & 7) << 4;
    const int vbyte0 = (srow >> 2) * 128 + (srow & 3) * 32;

    if (t < lim){
        size_t roff;
        const float *ksrc, *vsrc;
        if (t < ctxlen){
            const int page = ptab[b * MAX_PAGES + (t >> 4)];
            roff = ((size_t)(page * PAGE_SIZE + (t & 15)) * NUM_KV_HEADS + kvh) * HEAD_DIM;
            ksrc = kcache + roff; vsrc = vcache + roff;
        } else {
            roff = ((size_t)(b * Q_LEN + (t - ctxlen)) * NUM_KV_HEADS + kvh) * HEAD_DIM;
            ksrc = knew + roff; vsrc = vnew + roff;
        }
        const float* kr = ksrc + seg * 32;
        const float* vr = vsrc + seg * 32;
        #pragma unroll
        for (int i = 0; i < 4; ++i){
            float4 a  = *(const float4*)(kr + i * 8);
            float4 c4 = *(const float4*)(kr + i * 8 + 4);
            uint4 wv;
            wv.x = pack2(a.x, a.y);  wv.y = pack2(a.z, a.w);
            wv.z = pack2(c4.x, c4.y); wv.w = pack2(c4.z, c4.w);
            *(uint4*)(kdst + srow * 256 + ((seg * 64 + i * 16) ^ swz)) = wv;
        }
        #pragma unroll
        for (int db = 0; db < 2; ++db){
            const float4 a0 = *(const float4*)(vr + db * 16 + 0);
            const float4 a1 = *(const float4*)(vr + db * 16 + 4);
            const float4 a2 = *(const float4*)(vr + db * 16 + 8);
            const float4 a3 = *(const float4*)(vr + db * 16 + 12);
            uint4 w0, w1;
            w0.x = pack2(a0.x, a0.y); w0.y = pack2(a0.z, a0.w);
            w0.z = pack2(a1.x, a1.y); w0.w = pack2(a1.z, a1.w);
            w1.x = pack2(a2.x, a2.y); w1.y = pack2(a2.z, a2.w);
            w1.z = pack2(a3.x, a3.y); w1.w = pack2(a3.z, a3.w);
            const int dbk = seg * 2 + db;
            *(uint4*)(vdst + dbk * 2048 + vbyte0)      = w0;
            *(uint4*)(vdst + dbk * 2048 + vbyte0 + 16) = w1;
        }
    } else {
        const uint4 z = {0u, 0u, 0u, 0u};
        #pragma unroll
        for (int i = 0; i < 4; ++i)
            *(uint4*)(kdst + srow * 256 + ((seg * 64 + i * 16) ^ swz)) = z;
        #pragma unroll
        for (int db = 0; db < 2; ++db){
            const int dbk = seg * 2 + db;
            *(uint4*)(vdst + dbk * 2048 + vbyte0)      = z;
            *(uint4*)(vdst + dbk * 2048 + vbyte0 + 16) = z;
        }
    }
}

// ============================ attention kernel (r9 loop + counted-vmcnt pipeline) ============================
// LDS 64KB: K dbuf [2][16KB] at 0, V dbuf [2][16KB] at 32768. 2 blocks/CU.
// Per-chunk: lgkm(0) -> s_barrier (WAR) -> STAGE(ch+1) -> vmcnt(8) (RAW for ch; 8 newest in flight)
template<int NSPLIT>
__global__ __launch_bounds__(256, 2) void attn_kernel(
    const float* __restrict__ q,
    const int*   __restrict__ ctxlens,
    float*       __restrict__ out,
    const unsigned char* __restrict__ kimg,
    const unsigned char* __restrict__ vimg,
    unsigned char* __restrict__ part)
{
    __shared__ __align__(16) unsigned char lds[65536];

    const int tid  = threadIdx.x;
    const int w    = tid >> 6;
    const int lane = tid & 63;
    const int hh   = lane >> 4;
    const int cq   = lane & 15;

    const unsigned ldsb3 = (unsigned)(unsigned long long)(lds_as3_t*)(&lds[0]);

    const int fid   = blockIdx.x;
    const int item0 = fid / NSPLIT;               // 0..511, long items first
    const int seg   = fid % NSPLIT;

    const int b   = item0 & 7;
    const int kvh = (item0 >> 3) & 7;
    const int s32 = 7 - (item0 >> 6);             // s32=7 (longest) dispatched first

    const int s0 = s32 * 32;
    const int ctxlen = ctxlens[b];
    const int vlim = ctxlen + (s32 + 1) * 32;
    const int nch  = (vlim + 63) >> 6;
    const int lo   = (seg * nch) / NSPLIT;
    const int hi   = ((seg + 1) * nch) / NSPLIT;
    if (lo >= hi) return;
    const int hq = kvh * GQA + w;

    const unsigned char* kstream = kimg + (size_t)(b * 8 + kvh) * KSTREAM;
    const unsigned char* vstream = vimg + (size_t)(b * 8 + kvh) * KSTREAM;

    #define STAGE(CH, PB) do { \
        const unsigned char* kg_ = kstream + (size_t)(CH) * CHUNK_B + (w * 4096 + lane * 16); \
        const unsigned char* vg_ = vstream + (size_t)(CH) * CHUNK_B + (w * 4096 + lane * 16); \
        _Pragma("unroll") \
        for (int i_ = 0; i_ < 4; ++i_){ \
            GLD16(kg_ + i_ * 1024, lds + (PB) * CHUNK_B + w * 4096 + i_ * 1024); \
            GLD16(vg_ + i_ * 1024, lds + 32768 + (PB) * CHUNK_B + w * 4096 + i_ * 1024); \
        } \
    } while (0)

    STAGE(lo, lo & 1);   // 8 GLD16 per wave — oldest vmem ops

    // Q fragments (B-operand), two 16-row tiles, pre-scaled into log2 domain
    B8 qf[2][4];
    #pragma unroll
    for (int u = 0; u < 2; ++u){
        const float* qrow = q + (size_t)(b * Q_LEN + s0 + u * 16 + cq) * (NUM_HEADS * HEAD_DIM)
                              + hq * HEAD_DIM;
        #pragma unroll
        for (int c = 0; c < 4; ++c){
            const float4 f0 = *(const float4*)(qrow + c * 32 + 8 * hh);
            const float4 f1 = *(const float4*)(qrow + c * 32 + 8 * hh + 4);
            const float sc = SCALE * LOG2E;
            qf[u][c].u.x = pack2(f0.x * sc, f0.y * sc);
            qf[u][c].u.y = pack2(f0.z * sc, f0.w * sc);
            qf[u][c].u.z = pack2(f1.x * sc, f1.y * sc);
            qf[u][c].u.w = pack2(f1.z * sc, f1.w * sc);
        }
    }

    f32x4 acc[2][8] = {};
    float mrun[2] = {-1e30f, -1e30f};
    float lp[2]   = {0.f, 0.f};

    for (int ch = lo; ch < hi; ++ch){
        const int pb = ch & 1;

        // ---- pipeline head: WAR barrier, prefetch issue, counted RAW wait ----
        asm volatile("s_waitcnt lgkmcnt(0)" ::: "memory");   // all LDS reads of prev chunk drained
        __builtin_amdgcn_s_barrier();                        // raw barrier: no vmcnt drain
        __builtin_amdgcn_sched_barrier(0);
        if (ch + 1 < hi) {
            STAGE(ch + 1, pb ^ 1);                           // overwrite of pb^1 is WAR-safe now
            __builtin_amdgcn_sched_barrier(0);
            asm volatile("s_waitcnt vmcnt(8)" ::: "memory"); // chunk ch landed; 8 newest in flight
        } else {
            asm volatile("s_waitcnt vmcnt(0)" ::: "memory"); // last chunk: full drain
        }
        __builtin_amdgcn_sched_barrier(0);

        const int base = ch * 64;
        const unsigned kb = (unsigned)(pb * CHUNK_B);

        // ---------------- QK^T (swapped): st[u][tf] = S^T[t][q] ----------------
        __builtin_amdgcn_s_setprio(1);
        f32x4 st[2][4] = {};
        #pragma unroll
        for (int c = 0; c < 4; ++c){
            #pragma unroll
            for (int tf = 0; tf < 4; ++tf){
                const int trow = tf * 16 + cq;
                const unsigned byte = kb + trow * 256 + ((c * 64 + hh * 16) ^ ((trow & 7) << 4));
                B8 kf; kf.u = *(const uint4*)(lds + byte);
                st[0][tf] = __builtin_amdgcn_mfma_f32_16x16x32_bf16(kf.v, qf[0][c].v, st[0][tf], 0, 0, 0);
                st[1][tf] = __builtin_amdgcn_mfma_f32_16x16x32_bf16(kf.v, qf[1][c].v, st[1][tf], 0, 0, 0);
            }
        }
        __builtin_amdgcn_s_setprio(0);

        // ---------------- softmax (defer-max + deferred-l, base-2) ----------------
        B8 af[2][2];
        const bool interior = (base + 64 <= vlim);
        #pragma unroll
        for (int u = 0; u < 2; ++u){
            float p[4][4];
            float pm = -1e30f;
            if (interior){
                #pragma unroll
                for (int tf = 0; tf < 4; ++tf){
                    #pragma unroll
                    for (int r = 0; r < 4; ++r){
                        const float s = st[u][tf][r];
                        p[tf][r] = s;
                        pm = fmaxf(pm, s);
                    }
                }
            } else {
                #pragma unroll
                for (int tf = 0; tf < 4; ++tf){
                    #pragma unroll
                    for (int r = 0; r < 4; ++r){
                        const int t = base + tf * 16 + hh * 4 + r;
                        const float s = (t < vlim) ? st[u][tf][r] : -1e30f;
                        p[tf][r] = s;
                        pm = fmaxf(pm, s);
                    }
                }
            }
            pm = fmaxf(pm, __shfl_xor(pm, 16));
            pm = fmaxf(pm, __shfl_xor(pm, 32));

            if (!__all(pm <= mrun[u] + RESCALE_THR)){
                const float mnew  = fmaxf(mrun[u], pm);
                const float alpha = __builtin_amdgcn_exp2f(mrun[u] - mnew);
                mrun[u] = mnew;
                lp[u] *= alpha;
                float a4[4];
                #pragma unroll
                for (int r = 0; r < 4; ++r) a4[r] = __shfl(alpha, hh * 20 + r);
                #pragma unroll
                for (int dc = 0; dc < 8; ++dc){
                    #pragma unroll
                    for (int r = 0; r < 4; ++r) acc[u][dc][r] *= a4[r];
                }
            }
            const float m = mrun[u];
            float rsum = 0.f;
            #pragma unroll
            for (int tf = 0; tf < 4; ++tf){
                #pragma unroll
                for (int r = 0; r < 4; ++r){
                    const float e = __builtin_amdgcn_exp2f(p[tf][r] - m);
                    p[tf][r] = e;
                    rsum += e;
                }
            }
            lp[u] += rsum;

            // k-axis mapping: t(kk, 8hh+j) = 32kk + 16*(j>>2) + 4hh + (j&3)
            unsigned pk01[4], pk23[4];
            #pragma unroll
            for (int tf = 0; tf < 4; ++tf){
                pk01[tf] = pack2(p[tf][0], p[tf][1]);
                pk23[tf] = pack2(p[tf][2], p[tf][3]);
            }
            af[u][0].u.x = pk01[0]; af[u][0].u.y = pk23[0]; af[u][0].u.z = pk01[1]; af[u][0].u.w = pk23[1];
            af[u][1].u.x = pk01[2]; af[u][1].u.y = pk23[2]; af[u][1].u.z = pk01[3]; af[u][1].u.w = pk23[3];
        }

        // ---------------- PV via hardware transpose reads; vf shared by tiles ----------------
        {
            const unsigned trb = ldsb3 + 32768u + (unsigned)(pb * CHUNK_B) + (unsigned)(hh * 128 + cq * 8);
            unsigned long long r0,r1,r2,r3,r4,r5,r6,r7;
            B8 vf;
            __builtin_amdgcn_s_setprio(1);
            // ---- kk=0, dc=0..3 ----
            TRR(r0, trb, "0");     TRR(r1, trb, "512");
            TRR(r2, trb, "2048");  TRR(r3, trb, "2560");
            TRR(r4, trb, "4096");  TRR(r5, trb, "4608");
            TRR(r6, trb, "6144");  TRR(r7, trb, "6656");
            asm volatile("s_waitcnt lgkmcnt(0)" ::: "memory");
            __builtin_amdgcn_sched_barrier(0);
            vf.u.x=(unsigned)r0; vf.u.y=(unsigned)(r0>>32); vf.u.z=(unsigned)r1; vf.u.w=(unsigned)(r1>>32);
            acc[0][0] = __builtin_amdgcn_mfma_f32_16x16x32_bf16(af[0][0].v, vf.v, acc[0][0], 0, 0, 0);
            acc[1][0] = __builtin_amdgcn_mfma_f32_16x16x32_bf16(af[1][0].v, vf.v, acc[1][0], 0, 0, 0);
            vf.u.x=(unsigned)r2; vf.u.y=(unsigned)(r2>>32); vf.u.z=(unsigned)r3; vf.u.w=(unsigned)(r3>>32);
            acc[0][1] = __builtin_amdgcn_mfma_f32_16x16x32_bf16(af[0][0].v, vf.v, acc[0][1], 0, 0, 0);
            acc[1][1] = __builtin_amdgcn_mfma_f32_16x16x32_bf16(af[1][0].v, vf.v, acc[1][1], 0, 0, 0);
            vf.u.x=(unsigned)r4; vf.u.y=(unsigned)(r4>>32); vf.u.z=(unsigned)r5; vf.u.w=(unsigned)(r5>>32);
            acc[0][2] = __builtin_amdgcn_mfma_f32_16x16x32_bf16(af[0][0].v, vf.v, acc[0][2], 0, 0, 0);
            acc[1][2] = __builtin_amdgcn_mfma_f32_16x16x32_bf16(af[1][0].v, vf.v, acc[1][2], 0, 0, 0);
            vf.u.x=(unsigned)r6; vf.u.y=(unsigned)(r6>>32); vf.u.z=(unsigned)r7; vf.u.w=(unsigned)(r7>>32);
            acc[0][3] = __builtin_amdgcn_mfma_f32_16x16x32_bf16(af[0][0].v, vf.v, acc[0][3], 0, 0, 0);
            acc[1][3] = __builtin_amdgcn_mfma_f32_16x16x32_bf16(af[1][0].v, vf.v, acc[1][3], 0, 0, 0);
            // ---- kk=0, dc=4..7 ----
            TRR(r0, trb, "8192");  TRR(r1, trb, "8704");
            TRR(r2, trb, "10240"); TRR(r3, trb, "10752");
            TRR(r4, trb, "12288"); TRR(r5, trb, "12800");
            TRR(r6, trb, "14336"); TRR(r7, trb, "14848");
            asm volatile("s_waitcnt lgkmcnt(0)" ::: "memory");
            __builtin_amdgcn_sched_barrier(0);
            vf.u.x=(unsigned)r0; vf.u.y=(unsigned)(r0>>32); vf.u.z=(unsigned)r1; vf.u.w=(unsigned)(r1>>32);
            acc[0][4] = __builtin_amdgcn_mfma_f32_16x16x32_bf16(af[0][0].v, vf.v, acc[0][4], 0, 0, 0);
            acc[1][4] = __builtin_amdgcn_mfma_f32_16x16x32_bf16(af[1][0].v, vf.v, acc[1][4], 0, 0, 0);
            vf.u.x=(unsigned)r2; vf.u.y=(unsigned)(r2>>32); vf.u.z=(unsigned)r3; vf.u.w=(unsigned)(r3>>32);
            acc[0][5] = __builtin_amdgcn_mfma_f32_16x16x32_bf16(af[0][0].v, vf.v, acc[0][5], 0, 0, 0);
            acc[1][5] = __builtin_amdgcn_mfma_f32_16x16x32_bf16(af[1][0].v, vf.v, acc[1][5], 0, 0, 0);
            vf.u.x=(unsigned)r4; vf.u.y=(unsigned)(r4>>32); vf.u.z=(unsigned)r5; vf.u.w=(unsigned)(r5>>32);
            acc[0][6] = __builtin_amdgcn_mfma_f32_16x16x32_bf16(af[0][0].v, vf.v, acc[0][6], 0, 0, 0);
            acc[1][6] = __builtin_amdgcn_mfma_f32_16x16x32_bf16(af[1][0].v, vf.v, acc[1][6], 0, 0, 0);
            vf.u.x=(unsigned)r6; vf.u.y=(unsigned)(r6>>32); vf.u.z=(unsigned)r7; vf.u.w=(unsigned)(r7>>32);
            acc[0][7] = __builtin_amdgcn_mfma_f32_16x16x32_bf16(af[0][0].v, vf.v, acc[0][7], 0, 0, 0);
            acc[1][7] = __builtin_amdgcn_mfma_f32_16x16x32_bf16(af[1][0].v, vf.v, acc[1][7], 0, 0, 0);
            // ---- kk=1, dc=0..3 ----
            TRR(r0, trb, "1024");  TRR(r1, trb, "1536");
            TRR(r2, trb, "3072");  TRR(r3, trb, "3584");
            TRR(r4, trb, "5120");  TRR(r5, trb, "5632");
            TRR(r6, trb, "7168");  TRR(r7, trb, "7680");
            asm volatile("s_waitcnt lgkmcnt(0)" ::: "memory");
            __builtin_amdgcn_sched_barrier(0);
            vf.u.x=(unsigned)r0; vf.u.y=(unsigned)(r0>>32); vf.u.z=(unsigned)r1; vf.u.w=(unsigned)(r1>>32);
            acc[0][0] = __builtin_amdgcn_mfma_f32_16x16x32_bf16(af[0][1].v, vf.v, acc[0][0], 0, 0, 0);
            acc[1][0] = __builtin_amdgcn_mfma_f32_16x16x32_bf16(af[1][1].v, vf.v, acc[1][0], 0, 0, 0);
            vf.u.x=(unsigned)r2; vf.u.y=(unsigned)(r2>>32); vf.u.z=(unsigned)r3; vf.u.w=(unsigned)(r3>>32);
            acc[0][1] = __builtin_amdgcn_mfma_f32_16x16x32_bf16(af[0][1].v, vf.v, acc[0][1], 0, 0, 0);
            acc[1][1] = __builtin_amdgcn_mfma_f32_16x16x32_bf16(af[1][1].v, vf.v, acc[1][1], 0, 0, 0);
            vf.u.x=(unsigned)r4; vf.u.y=(unsigned)(r4>>32); vf.u.z=(unsigned)r5; vf.u.w=(unsigned)(r5>>32);
            acc[0][2] = __builtin_amdgcn_mfma_f32_16x16x32_bf16(af[0][1].v, vf.v, acc[0][2], 0, 0, 0);
            acc[1][2] = __builtin_amdgcn_mfma_f32_16x16x32_bf16(af[1][1].v, vf.v, acc[1][2], 0, 0, 0);
            vf.u.x=(unsigned)r6; vf.u.y=(unsigned)(r6>>32); vf.u.z=(unsigned)r7; vf.u.w=(unsigned)(r7>>32);
            acc[0][3] = __builtin_amdgcn_mfma_f32_16x16x32_bf16(af[0][1].v, vf.v, acc[0][3], 0, 0, 0);
            acc[1][3] = __builtin_amdgcn_mfma_f32_16x16x32_bf16(af[1][1].v, vf.v, acc[1][3], 0, 0, 0);
            // ---- kk=1, dc=4..7 ----
            TRR(r0, trb, "9216");  TRR(r1, trb, "9728");
            TRR(r2, trb, "11264"); TRR(r3, trb, "11776");
            TRR(r4, trb, "13312"); TRR(r5, trb, "13824");
            TRR(r6, trb, "15360"); TRR(r7, trb, "15872");
            asm volatile("s_waitcnt lgkmcnt(0)" ::: "memory");
            __builtin_amdgcn_sched_barrier(0);
            vf.u.x=(unsigned)r0; vf.u.y=(unsigned)(r0>>32); vf.u.z=(unsigned)r1; vf.u.w=(unsigned)(r1>>32);
            acc[0][4] = __builtin_amdgcn_mfma_f32_16x16x32_bf16(af[0][1].v, vf.v, acc[0][4], 0, 0, 0);
            acc[1][4] = __builtin_amdgcn_mfma_f32_16x16x32_bf16(af[1][1].v, vf.v, acc[1][4], 0, 0, 0);
            vf.u.x=(unsigned)r2; vf.u.y=(unsigned)(r2>>32); vf.u.z=(unsigned)r3; vf.u.w=(unsigned)(r3>>32);
            acc[0][5] = __builtin_amdgcn_mfma_f32_16x16x32_bf16(af[0][1].v, vf.v, acc[0][5], 0, 0, 0);
            acc[1][5] = __builtin_amdgcn_mfma_f32_16x16x32_bf16(af[1][1].v, vf.v, acc[1][5], 0, 0, 0);
            vf.u.x=(unsigned)r4; vf.u.y=(unsigned)(r4>>32); vf.u.z=(unsigned)r5; vf.u.w=(unsigned)(r5>>32);
            acc[0][6] = __builtin_amdgcn_mfma_f32_16x16x32_bf16(af[0][1].v, vf.v, acc[0][6], 0, 0, 0);
            acc[1][6] = __builtin_amdgcn_mfma_f32_16x16x32_bf16(af[1][1].v, vf.v, acc[1][6], 0, 0, 0);
            vf.u.x=(unsigned)r6; vf.u.y=(unsigned)(r6>>32); vf.u.z=(unsigned)r7; vf.u.w=(unsigned)(r7>>32);
            acc[0][7] = __builtin_amdgcn_mfma_f32_16x16x32_bf16(af[0][1].v, vf.v, acc[0][7], 0, 0, 0);
            acc[1][7] = __builtin_amdgcn_mfma_f32_16x16x32_bf16(af[1][1].v, vf.v, acc[1][7], 0, 0, 0);
            __builtin_amdgcn_s_setprio(0);
        }
        // no end-of-chunk barrier: next iteration's top barrier provides WAR separation
    }

    // ---------------- epilogue ----------------
    if (NSPLIT == 1){
        #pragma unroll
        for (int u = 0; u < 2; ++u){
            float l = lp[u];
            l += __shfl_xor(l, 16);
            l += __shfl_xor(l, 32);
            const float li = 1.0f / l;
            float li4[4];
            #pragma unroll
            for (int r = 0; r < 4; ++r) li4[r] = __shfl(li, hh * 20 + r);
            #pragma unroll
            for (int dc = 0; dc < 8; ++dc){
                #pragma unroll
                for (int r = 0; r < 4; ++r){
                    const int so = s0 + u * 16 + hh * 4 + r;
                    out[(size_t)(b * Q_LEN + so) * (NUM_HEADS * HEAD_DIM) + hq * HEAD_DIM + dc * 16 + cq]
                        = acc[u][dc][r] * li4[r];
                }
            }
        }
    } else {
        // bf16 fragment-order partial: fully coalesced
        unsigned char* pp = part + (size_t)fid * PBYTES;
        #pragma unroll
        for (int u = 0; u < 2; ++u){
            float l = lp[u];
            l += __shfl_xor(l, 16);
            l += __shfl_xor(l, 32);
            if (hh == 0){
                float2 ml; ml.x = mrun[u]; ml.y = l;
                *(float2*)(pp + 32768 + (size_t)(w * 32 + u * 16 + cq) * 8) = ml;
            }
            #pragma unroll
            for (int dc = 0; dc < 8; ++dc){
                uint2 pk;
                pk.x = pack2(acc[u][dc][0], acc[u][dc][1]);
                pk.y = pack2(acc[u][dc][2], acc[u][dc][3]);
                *(uint2*)(pp + (size_t)((((w * 2 + u) * 8 + dc) * 64 + lane)) * 8) = pk;
            }
        }
    }
    #undef STAGE
}

// ============================ merge kernel (coalesced, bf16 partials) ============================
template<int NSPLIT>
__global__ __launch_bounds__(256) void merge_kernel(
    const int* __restrict__ ctxlens,
    const unsigned char* __restrict__ part,
    float* __restrict__ out)
{
    __shared__ float s_w[NSPLIT][128];

    const int item0 = blockIdx.x;
    const int b   = item0 & 7;
    const int kvh = (item0 >> 3) & 7;
    const int s32 = 7 - (item0 >> 6);
    const int vlim = ctxlens[b] + (s32 + 1) * 32;
    const int nch  = (vlim + 63) >> 6;

    const int tid = threadIdx.x;

    bool act[NSPLIT];
    #pragma unroll
    for (int s = 0; s < NSPLIT; ++s){
        const int lo = (s * nch) / NSPLIT;
        const int hi = ((s + 1) * nch) / NSPLIT;
        act[s] = hi > lo;
    }

    if (tid < 128){
        float m[NSPLIT], l[NSPLIT];
        float M = -1e30f;
        #pragma unroll
        for (int s = 0; s < NSPLIT; ++s){
            if (act[s]){
                const float2 ml = *(const float2*)(part + (size_t)(item0 * NSPLIT + s) * PBYTES
                                                   + 32768 + (size_t)tid * 8);
                m[s] = ml.x; l[s] = ml.y;
                M = fmaxf(M, m[s]);
            }
        }
        float L = 0.f;
        float wg[NSPLIT];
        #pragma unroll
        for (int s = 0; s < NSPLIT; ++s){
            if (act[s]){
                wg[s] = __builtin_amdgcn_exp2f(m[s] - M);
                L += l[s] * wg[s];
            } else wg[s] = 0.f;
        }
        const float inv = 1.0f / L;
        #pragma unroll
        for (int s = 0; s < NSPLIT; ++s) s_w[s][tid] = wg[s] * inv;
    }
    __syncthreads();

    // O pass: 4096 uint2-slots; uint4 = 2 slots; 2048 uint4 / 256 threads = 8 each.
    for (int k = 0; k < 8; ++k){
        const int q4 = tid + k * 256;
        const int S0 = q4 * 2;
        const int g  = S0 >> 6;
        const int ln = S0 & 63;
        const int hD = g >> 4;
        const int u  = (g >> 3) & 1;
        const int dc = g & 7;
        const int hh = ln >> 4;
        const int cq = ln & 15;
        const int wbase = hD * 32 + u * 16 + hh * 4;

        float o0[4] = {0.f, 0.f, 0.f, 0.f};
        float o1[4] = {0.f, 0.f, 0.f, 0.f};
        #pragma unroll
        for (int s = 0; s < NSPLIT; ++s){
            if (!act[s]) continue;
            const uint4 v = *(const uint4*)(part + (size_t)(item0 * NSPLIT + s) * PBYTES
                                            + (size_t)q4 * 16);
            const float w0 = s_w[s][wbase + 0];
            const float w1 = s_w[s][wbase + 1];
            const float w2 = s_w[s][wbase + 2];
            const float w3 = s_w[s][wbase + 3];
            o0[0] += w0 * bflo(v.x); o0[1] += w1 * bfhi(v.x);
            o0[2] += w2 * bflo(v.y); o0[3] += w3 * bfhi(v.y);
            o1[0] += w0 * bflo(v.z); o1[1] += w1 * bfhi(v.z);
            o1[2] += w2 * bflo(v.w); o1[3] += w3 * bfhi(v.w);
        }
        float* obase = out + (size_t)(b * Q_LEN + s32 * 32 + u * 16 + hh * 4) * (NUM_HEADS * HEAD_DIM)
                     + (kvh * GQA + hD) * HEAD_DIM + dc * 16 + cq;
        #pragma unroll
        for (int r = 0; r < 4; ++r){
            float2 ov; ov.x = o0[r]; ov.y = o1[r];
            *(float2*)(obase + (size_t)r * (NUM_HEADS * HEAD_DIM)) = ov;
        }
    }
}

extern "C" void kernel_launch(void* const* d_in, const int* in_sizes, int n_in,
                              void* d_out, int out_size, void* d_ws, size_t ws_size,
                              hipStream_t stream) {
    const float* q  = (const float*)d_in[0];
    const float* k  = (const float*)d_in[1];
    const float* v  = (const float*)d_in[2];
    const float* kc = (const float*)d_in[3];
    const float* vc = (const float*)d_in[4];
    const int*   pt = (const int*)d_in[5];
    const int*   cl = (const int*)d_in[6];
    float* o = (float*)d_out;

    const size_t img_bytes = (size_t)64 * KSTREAM;            // 37,748,736 per image
    const size_t off_part  = 256 + 2 * img_bytes;             // 75,497,728
    const size_t need2 = off_part + (size_t)NITEMS * 2 * PBYTES;   // ~110 MB
    const size_t need1 = off_part;

    unsigned char* kimg = (unsigned char*)d_ws + 256;
    unsigned char* vimg = kimg + img_bytes;
    unsigned char* part = (unsigned char*)d_ws + off_part;

    prep_kernel<<<dim3(NCH_MAX, 8, 8), 256, 0, stream>>>(k, v, kc, vc, pt, cl, kimg, vimg);

    if (ws_size >= need2) {
        attn_kernel<2><<<NITEMS * 2, 256, 0, stream>>>(q, cl, o, kimg, vimg, part);
        merge_kernel<2><<<NITEMS, 256, 0, stream>>>(cl, part, o);
    } else if (ws_size >= need1) {
        attn_kernel<1><<<NITEMS, 256, 0, stream>>>(q, cl, o, kimg, vimg, part);
    }
}

// Round 12
// 135.756 us; speedup vs baseline: 1.5238x; 1.0221x over previous
//
#include <hip/hip_runtime.h>
#include <hip/hip_bf16.h>

#define NUM_HEADS   32
#define NUM_KV_HEADS 8
#define HEAD_DIM    128
#define GQA          4
#define Q_LEN      256
#define MAX_PAGES  128
#define PAGE_SIZE   16
#define SCALE 0.08838834764831845f
#define LOG2E 1.44269504088896340736f
#define RESCALE_THR 8.0f

// 64-token chunks (best measured per-chunk economics)
#define NCH_MAX   36
#define CHUNK_B   16384
#define KSTREAM   ((size_t)NCH_MAX * CHUNK_B)
#define NITEMS    512
#define PBYTES    33792                   // 32768 B bf16 O (frag order) + 1024 B ml

typedef __bf16 bf16x8 __attribute__((ext_vector_type(8)));
typedef float  f32x4  __attribute__((ext_vector_type(4)));

union B8 { uint4 u; bf16x8 v; };

__device__ __forceinline__ unsigned f2bf(float x){
    unsigned u = __builtin_bit_cast(unsigned, x);
    return (u + 0x7fffu + ((u >> 16) & 1u)) >> 16;
}
__device__ __forceinline__ unsigned pack2(float lo, float hi){
    return f2bf(lo) | (f2bf(hi) << 16);
}
__device__ __forceinline__ float bflo(unsigned h){
    return __builtin_bit_cast(float, h << 16);
}
__device__ __forceinline__ float bfhi(unsigned h){
    return __builtin_bit_cast(float, h & 0xffff0000u);
}

typedef __attribute__((address_space(3))) unsigned char lds_as3_t;
typedef const __attribute__((address_space(1))) void gas_v;
typedef __attribute__((address_space(3))) void las_v;

#define GLD16(g, l) __builtin_amdgcn_global_load_lds((gas_v*)(g), (las_v*)(l), 16, 0, 0)

#define TRR(dst, base, OFF) asm volatile("ds_read_b64_tr_b16 %0, %1 offset:" OFF \
                                         : "=v"(dst) : "v"(base))

// ============================ pre-pass: gather + bf16 + pre-swizzle (64-t chunks) ============================
__global__ __launch_bounds__(256) void prep_kernel(
    const float* __restrict__ knew,
    const float* __restrict__ vnew,
    const float* __restrict__ kcache,
    const float* __restrict__ vcache,
    const int*   __restrict__ ptab,
    const int*   __restrict__ ctxlens,
    unsigned char* __restrict__ kimg,
    unsigned char* __restrict__ vimg)
{
    const int ch  = blockIdx.x;
    const int kvh = blockIdx.y;
    const int b   = blockIdx.z;
    const int ctxlen = ctxlens[b];
    const int lim = ctxlen + Q_LEN;
    const int base = ch * 64;
    if (base >= lim) return;

    const int tid  = threadIdx.x;
    const int srow = tid >> 2;
    const int seg  = tid & 3;
    const int t    = base + srow;

    unsigned char* kdst = kimg + (size_t)(b * 8 + kvh) * KSTREAM + (size_t)ch * CHUNK_B;
    unsigned char* vdst = vimg + (size_t)(b * 8 + kvh) * KSTREAM + (size_t)ch * CHUNK_B;
    const int swz    = (srow & 7) << 4;
    const int vbyte0 = (srow >> 2) * 128 + (srow & 3) * 32;

    if (t < lim){
        size_t roff;
        const float *ksrc, *vsrc;
        if (t < ctxlen){
            const int page = ptab[b * MAX_PAGES + (t >> 4)];
            roff = ((size_t)(page * PAGE_SIZE + (t & 15)) * NUM_KV_HEADS + kvh) * HEAD_DIM;
            ksrc = kcache + roff; vsrc = vcache + roff;
        } else {
            roff = ((size_t)(b * Q_LEN + (t - ctxlen)) * NUM_KV_HEADS + kvh) * HEAD_DIM;
            ksrc = knew + roff; vsrc = vnew + roff;
        }
        const float* kr = ksrc + seg * 32;
        const float* vr = vsrc + seg * 32;
        #pragma unroll
        for (int i = 0; i < 4; ++i){
            float4 a  = *(const float4*)(kr + i * 8);
            float4 c4 = *(const float4*)(kr + i * 8 + 4);
            uint4 wv;
            wv.x = pack2(a.x, a.y);  wv.y = pack2(a.z, a.w);
            wv.z = pack2(c4.x, c4.y); wv.w = pack2(c4.z, c4.w);
            *(uint4*)(kdst + srow * 256 + ((seg * 64 + i * 16) ^ swz)) = wv;
        }
        #pragma unroll
        for (int db = 0; db < 2; ++db){
            const float4 a0 = *(const float4*)(vr + db * 16 + 0);
            const float4 a1 = *(const float4*)(vr + db * 16 + 4);
            const float4 a2 = *(const float4*)(vr + db * 16 + 8);
            const float4 a3 = *(const float4*)(vr + db * 16 + 12);
            uint4 w0, w1;
            w0.x = pack2(a0.x, a0.y); w0.y = pack2(a0.z, a0.w);
            w0.z = pack2(a1.x, a1.y); w0.w = pack2(a1.z, a1.w);
            w1.x = pack2(a2.x, a2.y); w1.y = pack2(a2.z, a2.w);
            w1.z = pack2(a3.x, a3.y); w1.w = pack2(a3.z, a3.w);
            const int dbk = seg * 2 + db;
            *(uint4*)(vdst + dbk * 2048 + vbyte0)      = w0;
            *(uint4*)(vdst + dbk * 2048 + vbyte0 + 16) = w1;
        }
    } else {
        const uint4 z = {0u, 0u, 0u, 0u};
        #pragma unroll
        for (int i = 0; i < 4; ++i)
            *(uint4*)(kdst + srow * 256 + ((seg * 64 + i * 16) ^ swz)) = z;
        #pragma unroll
        for (int db = 0; db < 2; ++db){
            const int dbk = seg * 2 + db;
            *(uint4*)(vdst + dbk * 2048 + vbyte0)      = z;
            *(uint4*)(vdst + dbk * 2048 + vbyte0 + 16) = z;
        }
    }
}

// ============================ attention kernel (early tr-read issue + lgkm-free softmax) ============================
// LDS 64KB: K dbuf [2][16KB] at 0, V dbuf [2][16KB] at 32768. 2 blocks/CU.
// Per-chunk: lgkm(0) -> s_barrier -> STAGE(ch+1) -> vmcnt(8) -> QK -> ISSUE 32 tr_reads ->
//            softmax (VALU-only steady state) -> lgkm(0) -> 32 PV MFMAs back-to-back.
template<int NSPLIT>
__global__ __launch_bounds__(256, 2) void attn_kernel(
    const float* __restrict__ q,
    const int*   __restrict__ ctxlens,
    float*       __restrict__ out,
    const unsigned char* __restrict__ kimg,
    const unsigned char* __restrict__ vimg,
    unsigned char* __restrict__ part)
{
    __shared__ __align__(16) unsigned char lds[65536];

    const int tid  = threadIdx.x;
    const int w    = tid >> 6;
    const int lane = tid & 63;
    const int hh   = lane >> 4;
    const int cq   = lane & 15;

    const unsigned ldsb3 = (unsigned)(unsigned long long)(lds_as3_t*)(&lds[0]);

    const int fid   = blockIdx.x;
    const int item0 = fid / NSPLIT;               // 0..511, long items first
    const int seg   = fid % NSPLIT;

    const int b   = item0 & 7;
    const int kvh = (item0 >> 3) & 7;
    const int s32 = 7 - (item0 >> 6);             // s32=7 (longest) dispatched first

    const int s0 = s32 * 32;
    const int ctxlen = ctxlens[b];
    const int vlim = ctxlen + (s32 + 1) * 32;
    const int nch  = (vlim + 63) >> 6;
    const int lo   = (seg * nch) / NSPLIT;
    const int hi   = ((seg + 1) * nch) / NSPLIT;
    if (lo >= hi) return;
    const int hq = kvh * GQA + w;

    const unsigned char* kstream = kimg + (size_t)(b * 8 + kvh) * KSTREAM;
    const unsigned char* vstream = vimg + (size_t)(b * 8 + kvh) * KSTREAM;

    #define STAGE(CH, PB) do { \
        const unsigned char* kg_ = kstream + (size_t)(CH) * CHUNK_B + (w * 4096 + lane * 16); \
        const unsigned char* vg_ = vstream + (size_t)(CH) * CHUNK_B + (w * 4096 + lane * 16); \
        _Pragma("unroll") \
        for (int i_ = 0; i_ < 4; ++i_){ \
            GLD16(kg_ + i_ * 1024, lds + (PB) * CHUNK_B + w * 4096 + i_ * 1024); \
            GLD16(vg_ + i_ * 1024, lds + 32768 + (PB) * CHUNK_B + w * 4096 + i_ * 1024); \
        } \
    } while (0)

    STAGE(lo, lo & 1);   // 8 GLD16 per wave — oldest vmem ops

    // Q fragments (B-operand), two 16-row tiles, pre-scaled into log2 domain
    B8 qf[2][4];
    #pragma unroll
    for (int u = 0; u < 2; ++u){
        const float* qrow = q + (size_t)(b * Q_LEN + s0 + u * 16 + cq) * (NUM_HEADS * HEAD_DIM)
                              + hq * HEAD_DIM;
        #pragma unroll
        for (int c = 0; c < 4; ++c){
            const float4 f0 = *(const float4*)(qrow + c * 32 + 8 * hh);
            const float4 f1 = *(const float4*)(qrow + c * 32 + 8 * hh + 4);
            const float sc = SCALE * LOG2E;
            qf[u][c].u.x = pack2(f0.x * sc, f0.y * sc);
            qf[u][c].u.y = pack2(f0.z * sc, f0.w * sc);
            qf[u][c].u.z = pack2(f1.x * sc, f1.y * sc);
            qf[u][c].u.w = pack2(f1.z * sc, f1.w * sc);
        }
    }

    f32x4 acc[2][8] = {};
    float mrun[2] = {-1e30f, -1e30f};
    float lp[2]   = {0.f, 0.f};

    for (int ch = lo; ch < hi; ++ch){
        const int pb = ch & 1;

        // ---- pipeline head: WAR barrier, prefetch issue, counted RAW wait ----
        asm volatile("s_waitcnt lgkmcnt(0)" ::: "memory");
        __builtin_amdgcn_s_barrier();
        __builtin_amdgcn_sched_barrier(0);
        if (ch + 1 < hi) {
            STAGE(ch + 1, pb ^ 1);
            __builtin_amdgcn_sched_barrier(0);
            asm volatile("s_waitcnt vmcnt(8)" ::: "memory");
        } else {
            asm volatile("s_waitcnt vmcnt(0)" ::: "memory");
        }
        __builtin_amdgcn_sched_barrier(0);

        const int base = ch * 64;
        const unsigned kb = (unsigned)(pb * CHUNK_B);

        // ---------------- QK^T (swapped): st[u][tf] = S^T[t][q] ----------------
        __builtin_amdgcn_s_setprio(1);
        f32x4 st[2][4] = {};
        #pragma unroll
        for (int c = 0; c < 4; ++c){
            #pragma unroll
            for (int tf = 0; tf < 4; ++tf){
                const int trow = tf * 16 + cq;
                const unsigned byte = kb + trow * 256 + ((c * 64 + hh * 16) ^ ((trow & 7) << 4));
                B8 kf; kf.u = *(const uint4*)(lds + byte);
                st[0][tf] = __builtin_amdgcn_mfma_f32_16x16x32_bf16(kf.v, qf[0][c].v, st[0][tf], 0, 0, 0);
                st[1][tf] = __builtin_amdgcn_mfma_f32_16x16x32_bf16(kf.v, qf[1][c].v, st[1][tf], 0, 0, 0);
            }
        }
        __builtin_amdgcn_s_setprio(0);

        // ---------------- EARLY ISSUE: all 32 V tr_reads (latency drains under softmax) ----------------
        const unsigned trb = ldsb3 + 32768u + (unsigned)(pb * CHUNK_B) + (unsigned)(hh * 128 + cq * 8);
        unsigned long long v00,v01,v02,v03,v04,v05,v06,v07,v08,v09,v10,v11,v12,v13,v14,v15;
        unsigned long long v16,v17,v18,v19,v20,v21,v22,v23,v24,v25,v26,v27,v28,v29,v30,v31;
        __builtin_amdgcn_sched_barrier(0);
        // kk=0, dc=0..7 (offsets dc*2048 + half*512)
        TRR(v00, trb, "0");     TRR(v01, trb, "512");
        TRR(v02, trb, "2048");  TRR(v03, trb, "2560");
        TRR(v04, trb, "4096");  TRR(v05, trb, "4608");
        TRR(v06, trb, "6144");  TRR(v07, trb, "6656");
        TRR(v08, trb, "8192");  TRR(v09, trb, "8704");
        TRR(v10, trb, "10240"); TRR(v11, trb, "10752");
        TRR(v12, trb, "12288"); TRR(v13, trb, "12800");
        TRR(v14, trb, "14336"); TRR(v15, trb, "14848");
        // kk=1, dc=0..7 (offsets dc*2048 + 1024 + half*512)
        TRR(v16, trb, "1024");  TRR(v17, trb, "1536");
        TRR(v18, trb, "3072");  TRR(v19, trb, "3584");
        TRR(v20, trb, "5120");  TRR(v21, trb, "5632");
        TRR(v22, trb, "7168");  TRR(v23, trb, "7680");
        TRR(v24, trb, "9216");  TRR(v25, trb, "9728");
        TRR(v26, trb, "11264"); TRR(v27, trb, "11776");
        TRR(v28, trb, "13312"); TRR(v29, trb, "13824");
        TRR(v30, trb, "15360"); TRR(v31, trb, "15872");
        __builtin_amdgcn_sched_barrier(0);

        // ---------------- softmax (shuffle-free defer-max; lgkm-free steady state) ----------------
        B8 af[2][2];
        const bool interior = (base + 64 <= vlim);
        #pragma unroll
        for (int u = 0; u < 2; ++u){
            float p[4][4];
            float pml = -1e30f;        // per-lane partial max over this lane's 16 t's
            if (interior){
                #pragma unroll
                for (int tf = 0; tf < 4; ++tf){
                    #pragma unroll
                    for (int r = 0; r < 4; ++r){
                        const float s = st[u][tf][r];
                        p[tf][r] = s;
                        pml = fmaxf(pml, s);
                    }
                }
            } else {
                #pragma unroll
                for (int tf = 0; tf < 4; ++tf){
                    #pragma unroll
                    for (int r = 0; r < 4; ++r){
                        const int t = base + tf * 16 + hh * 4 + r;
                        const float s = (t < vlim) ? st[u][tf][r] : -1e30f;
                        p[tf][r] = s;
                        pml = fmaxf(pml, s);
                    }
                }
            }
            // wave-max <= thr  <=>  all per-lane partial maxes <= thr (no cross-lane reduce needed)
            if (!__all(pml <= mrun[u] + RESCALE_THR)){
                float pm = fmaxf(pml, __shfl_xor(pml, 16));
                pm = fmaxf(pm, __shfl_xor(pm, 32));
                const float mnew  = fmaxf(mrun[u], pm);
                const float alpha = __builtin_amdgcn_exp2f(mrun[u] - mnew);
                mrun[u] = mnew;
                lp[u] *= alpha;
                float a4[4];
                #pragma unroll
                for (int r = 0; r < 4; ++r) a4[r] = __shfl(alpha, hh * 20 + r);
                #pragma unroll
                for (int dc = 0; dc < 8; ++dc){
                    #pragma unroll
                    for (int r = 0; r < 4; ++r) acc[u][dc][r] *= a4[r];
                }
            }
            const float m = mrun[u];
            float rsum = 0.f;
            #pragma unroll
            for (int tf = 0; tf < 4; ++tf){
                #pragma unroll
                for (int r = 0; r < 4; ++r){
                    const float e = __builtin_amdgcn_exp2f(p[tf][r] - m);
                    p[tf][r] = e;
                    rsum += e;
                }
            }
            lp[u] += rsum;

            // k-axis mapping: t(kk, 8hh+j) = 32kk + 16*(j>>2) + 4hh + (j&3)
            unsigned pk01[4], pk23[4];
            #pragma unroll
            for (int tf = 0; tf < 4; ++tf){
                pk01[tf] = pack2(p[tf][0], p[tf][1]);
                pk23[tf] = pack2(p[tf][2], p[tf][3]);
            }
            af[u][0].u.x = pk01[0]; af[u][0].u.y = pk23[0]; af[u][0].u.z = pk01[1]; af[u][0].u.w = pk23[1];
            af[u][1].u.x = pk01[2]; af[u][1].u.y = pk23[2]; af[u][1].u.z = pk01[3]; af[u][1].u.w = pk23[3];
        }

        // ---------------- PV: single wait, 32 MFMAs back-to-back ----------------
        {
            asm volatile("s_waitcnt lgkmcnt(0)" ::: "memory");
            __builtin_amdgcn_sched_barrier(0);
            __builtin_amdgcn_s_setprio(1);
            B8 vf;
            #define PVM(VA, VB, KK, DC) \
                vf.u.x=(unsigned)(VA); vf.u.y=(unsigned)((VA)>>32); \
                vf.u.z=(unsigned)(VB); vf.u.w=(unsigned)((VB)>>32); \
                acc[0][DC] = __builtin_amdgcn_mfma_f32_16x16x32_bf16(af[0][KK].v, vf.v, acc[0][DC], 0, 0, 0); \
                acc[1][DC] = __builtin_amdgcn_mfma_f32_16x16x32_bf16(af[1][KK].v, vf.v, acc[1][DC], 0, 0, 0);
            PVM(v00, v01, 0, 0)  PVM(v02, v03, 0, 1)  PVM(v04, v05, 0, 2)  PVM(v06, v07, 0, 3)
            PVM(v08, v09, 0, 4)  PVM(v10, v11, 0, 5)  PVM(v12, v13, 0, 6)  PVM(v14, v15, 0, 7)
            PVM(v16, v17, 1, 0)  PVM(v18, v19, 1, 1)  PVM(v20, v21, 1, 2)  PVM(v22, v23, 1, 3)
            PVM(v24, v25, 1, 4)  PVM(v26, v27, 1, 5)  PVM(v28, v29, 1, 6)  PVM(v30, v31, 1, 7)
            #undef PVM
            __builtin_amdgcn_s_setprio(0);
        }
        // no end-of-chunk barrier: next iteration's top barrier provides WAR separation
    }

    // ---------------- epilogue ----------------
    if (NSPLIT == 1){
        #pragma unroll
        for (int u = 0; u < 2; ++u){
            float l = lp[u];
            l += __shfl_xor(l, 16);
            l += __shfl_xor(l, 32);
            const float li = 1.0f / l;
            float li4[4];
            #pragma unroll
            for (int r = 0; r < 4; ++r) li4[r] = __shfl(li, hh * 20 + r);
            #pragma unroll
            for (int dc = 0; dc < 8; ++dc){
                #pragma unroll
                for (int r = 0; r < 4; ++r){
                    const int so = s0 + u * 16 + hh * 4 + r;
                    out[(size_t)(b * Q_LEN + so) * (NUM_HEADS * HEAD_DIM) + hq * HEAD_DIM + dc * 16 + cq]
                        = acc[u][dc][r] * li4[r];
                }
            }
        }
    } else {
        // bf16 fragment-order partial: fully coalesced
        unsigned char* pp = part + (size_t)fid * PBYTES;
        #pragma unroll
        for (int u = 0; u < 2; ++u){
            float l = lp[u];
            l += __shfl_xor(l, 16);
            l += __shfl_xor(l, 32);
            if (hh == 0){
                float2 ml; ml.x = mrun[u]; ml.y = l;
                *(float2*)(pp + 32768 + (size_t)(w * 32 + u * 16 + cq) * 8) = ml;
            }
            #pragma unroll
            for (int dc = 0; dc < 8; ++dc){
                uint2 pk;
                pk.x = pack2(acc[u][dc][0], acc[u][dc][1]);
                pk.y = pack2(acc[u][dc][2], acc[u][dc][3]);
                *(uint2*)(pp + (size_t)((((w * 2 + u) * 8 + dc) * 64 + lane)) * 8) = pk;
            }
        }
    }
    #undef STAGE
}

// ============================ merge kernel (coalesced, bf16 partials) ============================
template<int NSPLIT>
__global__ __launch_bounds__(256) void merge_kernel(
    const int* __restrict__ ctxlens,
    const unsigned char* __restrict__ part,
    float* __restrict__ out)
{
    __shared__ float s_w[NSPLIT][128];

    const int item0 = blockIdx.x;
    const int b   = item0 & 7;
    const int kvh = (item0 >> 3) & 7;
    const int s32 = 7 - (item0 >> 6);
    const int vlim = ctxlens[b] + (s32 + 1) * 32;
    const int nch  = (vlim + 63) >> 6;

    const int tid = threadIdx.x;

    bool act[NSPLIT];
    #pragma unroll
    for (int s = 0; s < NSPLIT; ++s){
        const int lo = (s * nch) / NSPLIT;
        const int hi = ((s + 1) * nch) / NSPLIT;
        act[s] = hi > lo;
    }

    if (tid < 128){
        float m[NSPLIT], l[NSPLIT];
        float M = -1e30f;
        #pragma unroll
        for (int s = 0; s < NSPLIT; ++s){
            if (act[s]){
                const float2 ml = *(const float2*)(part + (size_t)(item0 * NSPLIT + s) * PBYTES
                                                   + 32768 + (size_t)tid * 8);
                m[s] = ml.x; l[s] = ml.y;
                M = fmaxf(M, m[s]);
            }
        }
        float L = 0.f;
        float wg[NSPLIT];
        #pragma unroll
        for (int s = 0; s < NSPLIT; ++s){
            if (act[s]){
                wg[s] = __builtin_amdgcn_exp2f(m[s] - M);
                L += l[s] * wg[s];
            } else wg[s] = 0.f;
        }
        const float inv = 1.0f / L;
        #pragma unroll
        for (int s = 0; s < NSPLIT; ++s) s_w[s][tid] = wg[s] * inv;
    }
    __syncthreads();

    // O pass: 4096 uint2-slots; uint4 = 2 slots; 2048 uint4 / 256 threads = 8 each.
    for (int k = 0; k < 8; ++k){
        const int q4 = tid + k * 256;
        const int S0 = q4 * 2;
        const int g  = S0 >> 6;
        const int ln = S0 & 63;
        const int hD = g >> 4;
        const int u  = (g >> 3) & 1;
        const int dc = g & 7;
        const int hh = ln >> 4;
        const int cq = ln & 15;
        const int wbase = hD * 32 + u * 16 + hh * 4;

        float o0[4] = {0.f, 0.f, 0.f, 0.f};
        float o1[4] = {0.f, 0.f, 0.f, 0.f};
        #pragma unroll
        for (int s = 0; s < NSPLIT; ++s){
            if (!act[s]) continue;
            const uint4 v = *(const uint4*)(part + (size_t)(item0 * NSPLIT + s) * PBYTES
                                            + (size_t)q4 * 16);
            const float w0 = s_w[s][wbase + 0];
            const float w1 = s_w[s][wbase + 1];
            const float w2 = s_w[s][wbase + 2];
            const float w3 = s_w[s][wbase + 3];
            o0[0] += w0 * bflo(v.x); o0[1] += w1 * bfhi(v.x);
            o0[2] += w2 * bflo(v.y); o0[3] += w3 * bfhi(v.y);
            o1[0] += w0 * bflo(v.z); o1[1] += w1 * bfhi(v.z);
            o1[2] += w2 * bflo(v.w); o1[3] += w3 * bfhi(v.w);
        }
        float* obase = out + (size_t)(b * Q_LEN + s32 * 32 + u * 16 + hh * 4) * (NUM_HEADS * HEAD_DIM)
                     + (kvh * GQA + hD) * HEAD_DIM + dc * 16 + cq;
        #pragma unroll
        for (int r = 0; r < 4; ++r){
            float2 ov; ov.x = o0[r]; ov.y = o1[r];
            *(float2*)(obase + (size_t)r * (NUM_HEADS * HEAD_DIM)) = ov;
        }
    }
}

extern "C" void kernel_launch(void* const* d_in, const int* in_sizes, int n_in,
                              void* d_out, int out_size, void* d_ws, size_t ws_size,
                              hipStream_t stream) {
    const float* q  = (const float*)d_in[0];
    const float* k  = (const float*)d_in[1];
    const float* v  = (const float*)d_in[2];
    const float* kc = (const float*)d_in[3];
    const float* vc = (const float*)d_in[4];
    const int*   pt = (const int*)d_in[5];
    const int*   cl = (const int*)d_in[6];
    float* o = (float*)d_out;

    const size_t img_bytes = (size_t)64 * KSTREAM;            // 37,748,736 per image
    const size_t off_part  = 256 + 2 * img_bytes;             // 75,497,728
    const size_t need2 = off_part + (size_t)NITEMS * 2 * PBYTES;   // ~110 MB
    const size_t need1 = off_part;

    unsigned char* kimg = (unsigned char*)d_ws + 256;
    unsigned char* vimg = kimg + img_bytes;
    unsigned char* part = (unsigned char*)d_ws + off_part;

    prep_kernel<<<dim3(NCH_MAX, 8, 8), 256, 0, stream>>>(k, v, kc, vc, pt, cl, kimg, vimg);

    if (ws_size >= need2) {
        attn_kernel<2><<<NITEMS * 2, 256, 0, stream>>>(q, cl, o, kimg, vimg, part);
        merge_kernel<2><<<NITEMS, 256, 0, stream>>>(cl, part, o);
    } else if (ws_size >= need1) {
        attn_kernel<1><<<NITEMS, 256, 0, stream>>>(q, cl, o, kimg, vimg, part);
    }
}

// Round 13
// 113.497 us; speedup vs baseline: 1.8227x; 1.1961x over previous
//
#include <hip/hip_runtime.h>
#include <hip/hip_bf16.h>

#define NUM_HEADS   32
#define NUM_KV_HEADS 8
#define HEAD_DIM    128
#define GQA          4
#define Q_LEN      256
#define MAX_PAGES  128
#define PAGE_SIZE   16
#define SCALE 0.08838834764831845f
#define LOG2E 1.44269504088896340736f
#define RESCALE_THR 8.0f

// 64-token chunks (best measured per-chunk economics)
#define NCH_MAX   36
#define CHUNK_B   16384
#define KSTREAM   ((size_t)NCH_MAX * CHUNK_B)
#define NITEMS    512

typedef __bf16 bf16x8 __attribute__((ext_vector_type(8)));
typedef float  f32x4  __attribute__((ext_vector_type(4)));

union B8 { uint4 u; bf16x8 v; };

__device__ __forceinline__ unsigned f2bf(float x){
    unsigned u = __builtin_bit_cast(unsigned, x);
    return (u + 0x7fffu + ((u >> 16) & 1u)) >> 16;
}
__device__ __forceinline__ unsigned pack2(float lo, float hi){
    return f2bf(lo) | (f2bf(hi) << 16);
}

typedef __attribute__((address_space(3))) unsigned char lds_as3_t;
typedef const __attribute__((address_space(1))) void gas_v;
typedef __attribute__((address_space(3))) void las_v;

#define GLD16(g, l) __builtin_amdgcn_global_load_lds((gas_v*)(g), (las_v*)(l), 16, 0, 0)

#define TRR(dst, base, OFF) asm volatile("ds_read_b64_tr_b16 %0, %1 offset:" OFF \
                                         : "=v"(dst) : "v"(base))

// ============================ pre-pass: gather + bf16 + pre-swizzle (64-t chunks) ============================
__global__ __launch_bounds__(256) void prep_kernel(
    const float* __restrict__ knew,
    const float* __restrict__ vnew,
    const float* __restrict__ kcache,
    const float* __restrict__ vcache,
    const int*   __restrict__ ptab,
    const int*   __restrict__ ctxlens,
    unsigned char* __restrict__ kimg,
    unsigned char* __restrict__ vimg)
{
    const int ch  = blockIdx.x;
    const int kvh = blockIdx.y;
    const int b   = blockIdx.z;
    const int ctxlen = ctxlens[b];
    const int lim = ctxlen + Q_LEN;
    const int base = ch * 64;
    if (base >= lim) return;

    const int tid  = threadIdx.x;
    const int srow = tid >> 2;
    const int seg  = tid & 3;
    const int t    = base + srow;

    unsigned char* kdst = kimg + (size_t)(b * 8 + kvh) * KSTREAM + (size_t)ch * CHUNK_B;
    unsigned char* vdst = vimg + (size_t)(b * 8 + kvh) * KSTREAM + (size_t)ch * CHUNK_B;
    const int swz    = (srow & 7) << 4;
    const int vbyte0 = (srow >> 2) * 128 + (srow & 3) * 32;

    if (t < lim){
        size_t roff;
        const float *ksrc, *vsrc;
        if (t < ctxlen){
            const int page = ptab[b * MAX_PAGES + (t >> 4)];
            roff = ((size_t)(page * PAGE_SIZE + (t & 15)) * NUM_KV_HEADS + kvh) * HEAD_DIM;
            ksrc = kcache + roff; vsrc = vcache + roff;
        } else {
            roff = ((size_t)(b * Q_LEN + (t - ctxlen)) * NUM_KV_HEADS + kvh) * HEAD_DIM;
            ksrc = knew + roff; vsrc = vnew + roff;
        }
        const float* kr = ksrc + seg * 32;
        const float* vr = vsrc + seg * 32;
        #pragma unroll
        for (int i = 0; i < 4; ++i){
            float4 a  = *(const float4*)(kr + i * 8);
            float4 c4 = *(const float4*)(kr + i * 8 + 4);
            uint4 wv;
            wv.x = pack2(a.x, a.y);  wv.y = pack2(a.z, a.w);
            wv.z = pack2(c4.x, c4.y); wv.w = pack2(c4.z, c4.w);
            *(uint4*)(kdst + srow * 256 + ((seg * 64 + i * 16) ^ swz)) = wv;
        }
        #pragma unroll
        for (int db = 0; db < 2; ++db){
            const float4 a0 = *(const float4*)(vr + db * 16 + 0);
            const float4 a1 = *(const float4*)(vr + db * 16 + 4);
            const float4 a2 = *(const float4*)(vr + db * 16 + 8);
            const float4 a3 = *(const float4*)(vr + db * 16 + 12);
            uint4 w0, w1;
            w0.x = pack2(a0.x, a0.y); w0.y = pack2(a0.z, a0.w);
            w0.z = pack2(a1.x, a1.y); w0.w = pack2(a1.z, a1.w);
            w1.x = pack2(a2.x, a2.y); w1.y = pack2(a2.z, a2.w);
            w1.z = pack2(a3.x, a3.y); w1.w = pack2(a3.z, a3.w);
            const int dbk = seg * 2 + db;
            *(uint4*)(vdst + dbk * 2048 + vbyte0)      = w0;
            *(uint4*)(vdst + dbk * 2048 + vbyte0 + 16) = w1;
        }
    } else {
        const uint4 z = {0u, 0u, 0u, 0u};
        #pragma unroll
        for (int i = 0; i < 4; ++i)
            *(uint4*)(kdst + srow * 256 + ((seg * 64 + i * 16) ^ swz)) = z;
        #pragma unroll
        for (int db = 0; db < 2; ++db){
            const int dbk = seg * 2 + db;
            *(uint4*)(vdst + dbk * 2048 + vbyte0)      = z;
            *(uint4*)(vdst + dbk * 2048 + vbyte0 + 16) = z;
        }
    }
}

// ============================ attention kernel (r12 loop, direct output, no split) ============================
// LDS 64KB: K dbuf [2][16KB] at 0, V dbuf [2][16KB] at 32768. 2 blocks/CU.
// Per-chunk: lgkm(0) -> s_barrier -> STAGE(ch+1) -> vmcnt(8) -> QK -> ISSUE 32 tr_reads ->
//            softmax (VALU-only steady state) -> lgkm(0) -> 32 PV MFMAs back-to-back.
__global__ __launch_bounds__(256, 2) void attn_kernel(
    const float* __restrict__ q,
    const int*   __restrict__ ctxlens,
    float*       __restrict__ out,
    const unsigned char* __restrict__ kimg,
    const unsigned char* __restrict__ vimg)
{
    __shared__ __align__(16) unsigned char lds[65536];

    const int tid  = threadIdx.x;
    const int w    = tid >> 6;
    const int lane = tid & 63;
    const int hh   = lane >> 4;
    const int cq   = lane & 15;

    const unsigned ldsb3 = (unsigned)(unsigned long long)(lds_as3_t*)(&lds[0]);

    const int item0 = blockIdx.x;                 // 0..511, long items first

    const int b   = item0 & 7;
    const int kvh = (item0 >> 3) & 7;
    const int s32 = 7 - (item0 >> 6);             // s32=7 (longest) dispatched first

    const int s0 = s32 * 32;
    const int ctxlen = ctxlens[b];
    const int vlim = ctxlen + (s32 + 1) * 32;
    const int nch  = (vlim + 63) >> 6;
    const int hq = kvh * GQA + w;

    const unsigned char* kstream = kimg + (size_t)(b * 8 + kvh) * KSTREAM;
    const unsigned char* vstream = vimg + (size_t)(b * 8 + kvh) * KSTREAM;

    #define STAGE(CH, PB) do { \
        const unsigned char* kg_ = kstream + (size_t)(CH) * CHUNK_B + (w * 4096 + lane * 16); \
        const unsigned char* vg_ = vstream + (size_t)(CH) * CHUNK_B + (w * 4096 + lane * 16); \
        _Pragma("unroll") \
        for (int i_ = 0; i_ < 4; ++i_){ \
            GLD16(kg_ + i_ * 1024, lds + (PB) * CHUNK_B + w * 4096 + i_ * 1024); \
            GLD16(vg_ + i_ * 1024, lds + 32768 + (PB) * CHUNK_B + w * 4096 + i_ * 1024); \
        } \
    } while (0)

    STAGE(0, 0);   // 8 GLD16 per wave — oldest vmem ops

    // Q fragments (B-operand), two 16-row tiles, pre-scaled into log2 domain
    B8 qf[2][4];
    #pragma unroll
    for (int u = 0; u < 2; ++u){
        const float* qrow = q + (size_t)(b * Q_LEN + s0 + u * 16 + cq) * (NUM_HEADS * HEAD_DIM)
                              + hq * HEAD_DIM;
        #pragma unroll
        for (int c = 0; c < 4; ++c){
            const float4 f0 = *(const float4*)(qrow + c * 32 + 8 * hh);
            const float4 f1 = *(const float4*)(qrow + c * 32 + 8 * hh + 4);
            const float sc = SCALE * LOG2E;
            qf[u][c].u.x = pack2(f0.x * sc, f0.y * sc);
            qf[u][c].u.y = pack2(f0.z * sc, f0.w * sc);
            qf[u][c].u.z = pack2(f1.x * sc, f1.y * sc);
            qf[u][c].u.w = pack2(f1.z * sc, f1.w * sc);
        }
    }

    f32x4 acc[2][8] = {};
    float mrun[2] = {-1e30f, -1e30f};
    float lp[2]   = {0.f, 0.f};

    for (int ch = 0; ch < nch; ++ch){
        const int pb = ch & 1;

        // ---- pipeline head: WAR barrier, prefetch issue, counted RAW wait ----
        asm volatile("s_waitcnt lgkmcnt(0)" ::: "memory");
        __builtin_amdgcn_s_barrier();
        __builtin_amdgcn_sched_barrier(0);
        if (ch + 1 < nch) {
            STAGE(ch + 1, pb ^ 1);
            __builtin_amdgcn_sched_barrier(0);
            asm volatile("s_waitcnt vmcnt(8)" ::: "memory");
        } else {
            asm volatile("s_waitcnt vmcnt(0)" ::: "memory");
        }
        __builtin_amdgcn_sched_barrier(0);

        const int base = ch * 64;
        const unsigned kb = (unsigned)(pb * CHUNK_B);

        // ---------------- QK^T (swapped): st[u][tf] = S^T[t][q] ----------------
        __builtin_amdgcn_s_setprio(1);
        f32x4 st[2][4] = {};
        #pragma unroll
        for (int c = 0; c < 4; ++c){
            #pragma unroll
            for (int tf = 0; tf < 4; ++tf){
                const int trow = tf * 16 + cq;
                const unsigned byte = kb + trow * 256 + ((c * 64 + hh * 16) ^ ((trow & 7) << 4));
                B8 kf; kf.u = *(const uint4*)(lds + byte);
                st[0][tf] = __builtin_amdgcn_mfma_f32_16x16x32_bf16(kf.v, qf[0][c].v, st[0][tf], 0, 0, 0);
                st[1][tf] = __builtin_amdgcn_mfma_f32_16x16x32_bf16(kf.v, qf[1][c].v, st[1][tf], 0, 0, 0);
            }
        }
        __builtin_amdgcn_s_setprio(0);

        // ---------------- EARLY ISSUE: all 32 V tr_reads (latency drains under softmax) ----------------
        const unsigned trb = ldsb3 + 32768u + (unsigned)(pb * CHUNK_B) + (unsigned)(hh * 128 + cq * 8);
        unsigned long long v00,v01,v02,v03,v04,v05,v06,v07,v08,v09,v10,v11,v12,v13,v14,v15;
        unsigned long long v16,v17,v18,v19,v20,v21,v22,v23,v24,v25,v26,v27,v28,v29,v30,v31;
        __builtin_amdgcn_sched_barrier(0);
        // kk=0, dc=0..7 (offsets dc*2048 + half*512)
        TRR(v00, trb, "0");     TRR(v01, trb, "512");
        TRR(v02, trb, "2048");  TRR(v03, trb, "2560");
        TRR(v04, trb, "4096");  TRR(v05, trb, "4608");
        TRR(v06, trb, "6144");  TRR(v07, trb, "6656");
        TRR(v08, trb, "8192");  TRR(v09, trb, "8704");
        TRR(v10, trb, "10240"); TRR(v11, trb, "10752");
        TRR(v12, trb, "12288"); TRR(v13, trb, "12800");
        TRR(v14, trb, "14336"); TRR(v15, trb, "14848");
        // kk=1, dc=0..7 (offsets dc*2048 + 1024 + half*512)
        TRR(v16, trb, "1024");  TRR(v17, trb, "1536");
        TRR(v18, trb, "3072");  TRR(v19, trb, "3584");
        TRR(v20, trb, "5120");  TRR(v21, trb, "5632");
        TRR(v22, trb, "7168");  TRR(v23, trb, "7680");
        TRR(v24, trb, "9216");  TRR(v25, trb, "9728");
        TRR(v26, trb, "11264"); TRR(v27, trb, "11776");
        TRR(v28, trb, "13312"); TRR(v29, trb, "13824");
        TRR(v30, trb, "15360"); TRR(v31, trb, "15872");
        __builtin_amdgcn_sched_barrier(0);

        // ---------------- softmax (shuffle-free defer-max; lgkm-free steady state) ----------------
        B8 af[2][2];
        const bool interior = (base + 64 <= vlim);
        #pragma unroll
        for (int u = 0; u < 2; ++u){
            float p[4][4];
            float pml = -1e30f;        // per-lane partial max over this lane's 16 t's
            if (interior){
                #pragma unroll
                for (int tf = 0; tf < 4; ++tf){
                    #pragma unroll
                    for (int r = 0; r < 4; ++r){
                        const float s = st[u][tf][r];
                        p[tf][r] = s;
                        pml = fmaxf(pml, s);
                    }
                }
            } else {
                #pragma unroll
                for (int tf = 0; tf < 4; ++tf){
                    #pragma unroll
                    for (int r = 0; r < 4; ++r){
                        const int t = base + tf * 16 + hh * 4 + r;
                        const float s = (t < vlim) ? st[u][tf][r] : -1e30f;
                        p[tf][r] = s;
                        pml = fmaxf(pml, s);
                    }
                }
            }
            // wave-max <= thr  <=>  all per-lane partial maxes <= thr (no cross-lane reduce needed)
            if (!__all(pml <= mrun[u] + RESCALE_THR)){
                float pm = fmaxf(pml, __shfl_xor(pml, 16));
                pm = fmaxf(pm, __shfl_xor(pm, 32));
                const float mnew  = fmaxf(mrun[u], pm);
                const float alpha = __builtin_amdgcn_exp2f(mrun[u] - mnew);
                mrun[u] = mnew;
                lp[u] *= alpha;
                float a4[4];
                #pragma unroll
                for (int r = 0; r < 4; ++r) a4[r] = __shfl(alpha, hh * 20 + r);
                #pragma unroll
                for (int dc = 0; dc < 8; ++dc){
                    #pragma unroll
                    for (int r = 0; r < 4; ++r) acc[u][dc][r] *= a4[r];
                }
            }
            const float m = mrun[u];
            float rsum = 0.f;
            #pragma unroll
            for (int tf = 0; tf < 4; ++tf){
                #pragma unroll
                for (int r = 0; r < 4; ++r){
                    const float e = __builtin_amdgcn_exp2f(p[tf][r] - m);
                    p[tf][r] = e;
                    rsum += e;
                }
            }
            lp[u] += rsum;

            // k-axis mapping: t(kk, 8hh+j) = 32kk + 16*(j>>2) + 4hh + (j&3)
            unsigned pk01[4], pk23[4];
            #pragma unroll
            for (int tf = 0; tf < 4; ++tf){
                pk01[tf] = pack2(p[tf][0], p[tf][1]);
                pk23[tf] = pack2(p[tf][2], p[tf][3]);
            }
            af[u][0].u.x = pk01[0]; af[u][0].u.y = pk23[0]; af[u][0].u.z = pk01[1]; af[u][0].u.w = pk23[1];
            af[u][1].u.x = pk01[2]; af[u][1].u.y = pk23[2]; af[u][1].u.z = pk01[3]; af[u][1].u.w = pk23[3];
        }

        // ---------------- PV: single wait, 32 MFMAs back-to-back ----------------
        {
            asm volatile("s_waitcnt lgkmcnt(0)" ::: "memory");
            __builtin_amdgcn_sched_barrier(0);
            __builtin_amdgcn_s_setprio(1);
            B8 vf;
            #define PVM(VA, VB, KK, DC) \
                vf.u.x=(unsigned)(VA); vf.u.y=(unsigned)((VA)>>32); \
                vf.u.z=(unsigned)(VB); vf.u.w=(unsigned)((VB)>>32); \
                acc[0][DC] = __builtin_amdgcn_mfma_f32_16x16x32_bf16(af[0][KK].v, vf.v, acc[0][DC], 0, 0, 0); \
                acc[1][DC] = __builtin_amdgcn_mfma_f32_16x16x32_bf16(af[1][KK].v, vf.v, acc[1][DC], 0, 0, 0);
            PVM(v00, v01, 0, 0)  PVM(v02, v03, 0, 1)  PVM(v04, v05, 0, 2)  PVM(v06, v07, 0, 3)
            PVM(v08, v09, 0, 4)  PVM(v10, v11, 0, 5)  PVM(v12, v13, 0, 6)  PVM(v14, v15, 0, 7)
            PVM(v16, v17, 1, 0)  PVM(v18, v19, 1, 1)  PVM(v20, v21, 1, 2)  PVM(v22, v23, 1, 3)
            PVM(v24, v25, 1, 4)  PVM(v26, v27, 1, 5)  PVM(v28, v29, 1, 6)  PVM(v30, v31, 1, 7)
            #undef PVM
            __builtin_amdgcn_s_setprio(0);
        }
        // no end-of-chunk barrier: next iteration's top barrier provides WAR separation
    }

    // ---------------- epilogue: normalize + direct write ----------------
    #pragma unroll
    for (int u = 0; u < 2; ++u){
        float l = lp[u];
        l += __shfl_xor(l, 16);
        l += __shfl_xor(l, 32);
        const float li = 1.0f / l;
        float li4[4];
        #pragma unroll
        for (int r = 0; r < 4; ++r) li4[r] = __shfl(li, hh * 20 + r);
        #pragma unroll
        for (int dc = 0; dc < 8; ++dc){
            #pragma unroll
            for (int r = 0; r < 4; ++r){
                const int so = s0 + u * 16 + hh * 4 + r;
                out[(size_t)(b * Q_LEN + so) * (NUM_HEADS * HEAD_DIM) + hq * HEAD_DIM + dc * 16 + cq]
                    = acc[u][dc][r] * li4[r];
            }
        }
    }
    #undef STAGE
}

extern "C" void kernel_launch(void* const* d_in, const int* in_sizes, int n_in,
                              void* d_out, int out_size, void* d_ws, size_t ws_size,
                              hipStream_t stream) {
    const float* q  = (const float*)d_in[0];
    const float* k  = (const float*)d_in[1];
    const float* v  = (const float*)d_in[2];
    const float* kc = (const float*)d_in[3];
    const float* vc = (const float*)d_in[4];
    const int*   pt = (const int*)d_in[5];
    const int*   cl = (const int*)d_in[6];
    float* o = (float*)d_out;

    unsigned char* kimg = (unsigned char*)d_ws + 256;
    unsigned char* vimg = kimg + (size_t)64 * KSTREAM;

    prep_kernel<<<dim3(NCH_MAX, 8, 8), 256, 0, stream>>>(k, v, kc, vc, pt, cl, kimg, vimg);
    attn_kernel<<<NITEMS, 256, 0, stream>>>(q, cl, o, kimg, vimg);
}